// Round 8
// baseline (454.936 us; speedup 1.0000x reference)
//
#include <hip/hip_runtime.h>
#include <math.h>

#define PI_F 3.14159265358979323846f

typedef __bf16  bf16x8  __attribute__((ext_vector_type(8)));
typedef float   floatx4 __attribute__((ext_vector_type(4)));

__device__ __forceinline__ float gelu_tanh(float x){
  float x3 = x*x*x;
  float t = tanhf(0.7978845608028654f*(x + 0.044715f*x3));
  return 0.5f*x*(1.0f+t);
}

// async global->LDS 16B per lane; LDS dest = wave-uniform base + lane*16
__device__ __forceinline__ void gl_lds16(const void* g, void* l){
  __builtin_amdgcn_global_load_lds(
      (const __attribute__((address_space(1))) void*)(uintptr_t)g,
      (__attribute__((address_space(3))) void*)(uintptr_t)l,
      16, 0, 0);
}

// ---------------- prep: zfill K buffers + wcvt cm_w2 + wlat (one dispatch) ----------------
__global__ __launch_bounds__(256) void prep_k(const float* __restrict__ w2in,
                                              __bf16* __restrict__ wt2,
                                              __bf16* __restrict__ kbuf,
                                              const float* __restrict__ lat,
                                              float* __restrict__ wlat){
  int b = blockIdx.x, t = threadIdx.x;
  if(b < 1440){
    int i = b*256 + t;
    if(i < 368640) kbuf[i] = (__bf16)0.f;
  } else if(b < 4512){
    int idx = (b-1440)*256 + t;   // 786432 total
    int n = idx >> 10, k = idx & 1023;      // wt2[n][k] = w2[k][n], N=768,K=1024
    wt2[idx] = (__bf16)w2in[(size_t)k*768 + n];
  } else {
    if(t < 91) wlat[t] = cosf(lat[t]);
    __syncthreads();
    if(t == 0){
      float dlat = lat[1]-lat[0];
      float s4 = sinf(dlat*0.25f);
      float pw = s4*s4 / sinf(dlat*0.5f);
      if(wlat[0]  < 0.001f) wlat[0]  = pw;
      if(wlat[90] < 0.001f) wlat[90] = pw;
    }
  }
}

// ---------------- GN1 partial stats + plain bf16 cast of u_src (512 blocks) ----------------
__global__ __launch_bounds__(256) void gn1cast_k(const float* __restrict__ x,
                                                 __bf16* __restrict__ xa,
                                                 float* __restrict__ part, int npos){
  int c = threadIdx.x;
  float s=0.f, q=0.f;
  for(int p=blockIdx.x; p<npos; p+=gridDim.x){
    float v = x[p*256 + c];
    xa[p*256 + c] = (__bf16)v;
    s += v; q += v*v;
  }
  __shared__ float ss[256], sq[256];
  ss[c]=s; sq[c]=q;
  __syncthreads();
  if((c&7)==0){
    float a=0.f,b=0.f;
    #pragma unroll
    for(int k=0;k<8;k++){ a+=ss[c+k]; b+=sq[c+k]; }
    int g=c>>3;
    part[(blockIdx.x*32+g)*2+0]=a;
    part[(blockIdx.x*32+g)*2+1]=b;
  }
}

// ---------------- parallel GN final reduce ----------------
__global__ __launch_bounds__(256) void gn_final_par(const float* __restrict__ part,
                                                    float* __restrict__ stats,
                                                    int nblk, float invN){
  int t = threadIdx.x;
  int g = t & 31, ch = t >> 5;       // 8 chunks
  float s=0.f,q=0.f;
  for(int b=ch; b<nblk; b+=8){
    s += part[(b*32+g)*2+0];
    q += part[(b*32+g)*2+1];
  }
  __shared__ float ss[256], sq[256];
  ss[t]=s; sq[t]=q;
  __syncthreads();
  if(t<32){
    float a=0.f,bq=0.f;
    #pragma unroll
    for(int c=0;c<8;c++){ a+=ss[c*32+t]; bq+=sq[c*32+t]; }
    float m = a*invN;
    float v = bq*invN - m*m;
    stats[t*2+0]=m;
    stats[t*2+1]=rsqrtf(v+1e-5f);
  }
}

// ---------------- fold GN1 into W1 ----------------
__global__ __launch_bounds__(256) void w1fix_k(const float* __restrict__ w1,
                                               const float* __restrict__ b1,
                                               const float* __restrict__ stats,
                                               const float* __restrict__ gw,
                                               const float* __restrict__ gb,
                                               __bf16* __restrict__ wt1,
                                               float* __restrict__ b1p){
  int n = blockIdx.x, c = threadIdx.x;
  int g = c>>3;
  float m = stats[g*2+0], r = stats[g*2+1];
  float s = r*gw[c];
  float t = gb[c] - m*s;
  float w = w1[(size_t)c*1024 + n];
  wt1[(size_t)n*256 + c] = (__bf16)(s*w);
  __shared__ float red[256];
  red[c] = t*w; __syncthreads();
  for(int st=128; st>0; st>>=1){ if(c<st) red[c]+=red[c+st]; __syncthreads(); }
  if(c==0) b1p[n] = b1[n] + red[0];
}

// ---------------- fold GN2 into mh_w ----------------
__global__ __launch_bounds__(256) void w3fix_k(const float* __restrict__ mhw,
                                               const float* __restrict__ part2,
                                               const float* __restrict__ gw,
                                               const float* __restrict__ gb,
                                               __bf16* __restrict__ wt3,
                                               float* __restrict__ b3){
  __shared__ float st[16];
  __shared__ float ps[256], pq[256];
  int n = blockIdx.x, t = threadIdx.x;
  {
    int g = t & 7, ch = t >> 3;
    float s=0.f,q=0.f;
    for(int i=ch; i<91; i+=32){
      s += part2[(g*91+i)*2+0];
      q += part2[(g*91+i)*2+1];
    }
    ps[t]=s; pq[t]=q;
    __syncthreads();
    if(t<8){
      float a=0.f,bq=0.f;
      #pragma unroll
      for(int c=0;c<32;c++){ a+=ps[c*8+t]; bq+=pq[c*8+t]; }
      float m = a*(1.f/1048320.f);
      float v = bq*(1.f/1048320.f) - m*m;
      st[t*2+0]=m; st[t*2+1]=rsqrtf(v+1e-5f);
    }
    __syncthreads();
  }
  float bp=0.f;
  #pragma unroll
  for(int l=0;l<2;l++){
    int cc = t + l*256;
    int g = cc>>6;
    float m = st[g*2+0], r = st[g*2+1];
    float s = r*gw[cc];
    float tt = gb[cc] - m*s;
    float w = mhw[(size_t)cc*256 + n];
    wt3[(size_t)n*512 + cc] = (__bf16)(s*w);
    bp += tt*w;
  }
  __shared__ float red[256];
  red[t]=bp; __syncthreads();
  for(int stp=128;stp>0;stp>>=1){ if(t<stp) red[t]+=red[t+stp]; __syncthreads(); }
  if(t==0) b3[n]=red[0];
}

// ---------------- MFMA bf16 GEMM: BK=64, global_load_lds staging, XOR-swizzled LDS ----------------
// Grid (row-fastest): all col-blocks of an A-row-tile share one XCD -> A fetched once/XCD.
// Swizzle: 16B chunk c of LDS row r stored at phys chunk c ^ (r&7) -> 2-way banks (free).
// OUTMODE: 0 = fp32 C, 1 = bf16 C, 2 = u2-split (cols<512 -> VB bf16 [h][m][j][c]; cols>=512 -> UM bf16 [pos][256])
template<int ACT, int OUTMODE>
__global__ __launch_bounds__(256) void gemm_ld(const __bf16* __restrict__ A,
                                               const __bf16* __restrict__ Bt,
                                               const float* __restrict__ bias,
                                               void* __restrict__ Cp,
                                               __bf16* __restrict__ VB,
                                               __bf16* __restrict__ UM,
                                               int M, int N, int K)
{
  __shared__ __bf16 As[128][64];
  __shared__ __bf16 Bs[128][64];
  const int tid  = threadIdx.x;
  const int lane = tid & 63, wave = tid >> 6;
  const int row0 = blockIdx.x*128, col0 = blockIdx.y*128;
  const int lrow = lane >> 3;                       // 8 rows per wave-load
  const int csw  = ((lane&7) ^ (lrow&7)) * 8;       // swizzled source chunk
  const int wr = (wave >> 1)*64, wc = (wave & 1)*64;
  const int m16 = lane & 15, quad = lane >> 4;

  const __bf16* Ag = A  + (size_t)(row0 + wave*32 + lrow)*K + csw;
  const __bf16* Bg = Bt + (size_t)(col0 + wave*32 + lrow)*K + csw;

  floatx4 acc[4][4];
  #pragma unroll
  for(int i=0;i<4;i++)
    #pragma unroll
    for(int j=0;j<4;j++) acc[i][j] = (floatx4)0.f;

  const int kiters = K >> 6;
  for(int kk=0; kk<kiters; kk++){
    __syncthreads();
    #pragma unroll
    for(int L=0;L<4;L++){
      gl_lds16(Ag + (size_t)(L*8)*K, &As[wave*32 + L*8][0]);
      gl_lds16(Bg + (size_t)(L*8)*K, &Bs[wave*32 + L*8][0]);
    }
    Ag += 64; Bg += 64;
    __syncthreads();

    #pragma unroll
    for(int sub=0; sub<2; sub++){
      const int pa = (((sub<<2)+quad) ^ (m16&7)) << 3;
      bf16x8 af[4], bfv[4];
      #pragma unroll
      for(int ti=0;ti<4;ti++) af[ti]  = *(const bf16x8*)&As[wr + ti*16 + m16][pa];
      #pragma unroll
      for(int tj=0;tj<4;tj++) bfv[tj] = *(const bf16x8*)&Bs[wc + tj*16 + m16][pa];
      #pragma unroll
      for(int ti=0;ti<4;ti++)
        #pragma unroll
        for(int tj=0;tj<4;tj++)
          acc[ti][tj] = __builtin_amdgcn_mfma_f32_16x16x32_bf16(af[ti], bfv[tj], acc[ti][tj], 0,0,0);
    }
  }

  #pragma unroll
  for(int ti=0;ti<4;ti++){
    #pragma unroll
    for(int reg=0;reg<4;reg++){
      int gr = row0 + wr + ti*16 + quad*4 + reg;
      if(gr >= M) continue;
      int jj = gr/180, mm = gr - jj*180;   // only used for OUTMODE 2
      #pragma unroll
      for(int tj=0;tj<4;tj++){
        int gc = col0 + wc + tj*16 + m16;
        float v = acc[ti][tj][reg];
        if(bias) v += bias[gc];
        if(ACT==1) v = gelu_tanh(v);
        if(OUTMODE==2){
          if(gc < 512){
            int hh = gc>>6, cc = gc&63;
            VB[(((size_t)(hh*180+mm)*91)+jj)*64 + cc] = (__bf16)v;
          } else {
            UM[(size_t)gr*256 + (gc-512)] = (__bf16)v;
          }
        } else if(OUTMODE==1){
          ((__bf16*)Cp)[(size_t)gr*N + gc] = (__bf16)v;
        } else {
          ((float*)Cp)[(size_t)gr*N + gc]  = v;
        }
      }
    }
  }
}

// ---------------- merged mean + pooling MLP: one dispatch, 271 blocks ----------------
__device__ __forceinline__ void pool_core(int r, int t, float y,
    const float* __restrict__ lnw, const float* __restrict__ lnb,
    const float* __restrict__ w1, const float* __restrict__ b1,
    const float* __restrict__ w2, const float* __restrict__ b2,
    float* __restrict__ out,
    float* xn, float* red, float* g){
  red[t]=y; __syncthreads();
  for(int s=128;s>0;s>>=1){ if(t<s) red[t]+=red[t+s]; __syncthreads(); }
  float m = red[0]*(1.f/256.f); __syncthreads();
  float d = y-m; red[t]=d*d; __syncthreads();
  for(int s=128;s>0;s>>=1){ if(t<s) red[t]+=red[t+s]; __syncthreads(); }
  float var = red[0]*(1.f/256.f);
  __syncthreads();
  xn[t] = d*rsqrtf(var+1e-5f)*lnw[t]+lnb[t];
  __syncthreads();
  float s1=b1[t], s2=b1[256+t];
  for(int c=0;c<256;c++){ float xv=xn[c]; s1 += xv*w1[c*512+t]; s2 += xv*w1[c*512+256+t]; }
  g[t] = gelu_tanh(s1)*s2;
  __syncthreads();
  float o=b2[t];
  for(int c=0;c<256;c++) o += g[c]*w2[c*256+t];
  out[r*256+t]=o;
}

__global__ __launch_bounds__(256) void mpool_k(
    const __bf16* __restrict__ um, const float* __restrict__ wlat,
    const float* __restrict__ tl_inw, const float* __restrict__ tl_lnw, const float* __restrict__ tl_lnb,
    const float* __restrict__ tl_w1, const float* __restrict__ tl_b1,
    const float* __restrict__ tl_w2, const float* __restrict__ tl_b2,
    const float* __restrict__ ta_inw, const float* __restrict__ ta_lnw, const float* __restrict__ ta_lnb,
    const float* __restrict__ ta_w1, const float* __restrict__ ta_b1,
    const float* __restrict__ ta_w2, const float* __restrict__ ta_b2,
    float* __restrict__ ulsrc, float* __restrict__ uasrc){
  __shared__ float xs[256], xn[256], red[256], g[256];
  int b = blockIdx.x, t = threadIdx.x;
  if(b < 180){
    float s=0.f;
    for(int j=0;j<91;j++) s += (float)um[(size_t)(j*180+b)*256 + t];
    xs[t] = s*(1.0f/91.0f);
    __syncthreads();
    float y=0.f;
    for(int c=0;c<256;c++) y += xs[c]*tl_inw[c*256+t];
    pool_core(b, t, y, tl_lnw, tl_lnb, tl_w1, tl_b1, tl_w2, tl_b2, ulsrc, xn, red, g);
  } else {
    int r = b-180;
    const __bf16* base = um + (size_t)r*180*256 + t;
    float s=0.f;
    for(int m=0;m<180;m++) s += (float)base[(size_t)m*256];
    xs[t] = s*(1.0f/180.0f);
    __syncthreads();
    float y=0.f;
    for(int c=0;c<256;c++) y += xs[c]*ta_inw[c*256+t];
    y *= wlat[r];
    pool_core(r, t, y, ta_lnw, ta_lnb, ta_w1, ta_b1, ta_w2, ta_b2, uasrc, xn, red, g);
  }
}

// ---------------- merged k-projection, transposed output out[col][r] ----------------
__global__ __launch_bounds__(256) void rowmmT2_k(const float* __restrict__ ulsrc,
                                                 const float* __restrict__ uasrc,
                                                 const float* __restrict__ wlong,
                                                 const float* __restrict__ wlatk,
                                                 float* __restrict__ klkl,
                                                 float* __restrict__ klka){
  int b = blockIdx.x, t = threadIdx.x;
  const float* X; const float* W; float* out; int r, R;
  if(b < 180){ r=b;     X=ulsrc; W=wlong; out=klkl; R=180; }
  else       { r=b-180; X=uasrc; W=wlatk; out=klka; R=91;  }
  int j = blockIdx.y*256 + t;
  __shared__ float xs[256];
  xs[t] = X[r*256 + t];
  __syncthreads();
  float s = 0.f;
  for(int c=0;c<256;c++) s += xs[c]*W[(size_t)c*1536 + j];
  out[(size_t)j*R + r] = s;
}

// ---------------- merged modulation tables, transposed out[(h*192+d)][m] ----------------
__global__ __launch_bounds__(256) void modu2_k(const float* __restrict__ lon,
                                               const float* __restrict__ lat,
                                               const float* __restrict__ flong,
                                               const float* __restrict__ flat,
                                               const float* __restrict__ wlong,
                                               const float* __restrict__ wlatm,
                                               float* __restrict__ modul,
                                               float* __restrict__ modua){
  int b = blockIdx.x, t = threadIdx.x;
  const float* coord; const float* freqs; const float* W; float* out;
  int h, m, nm, nk, periodic;
  if(b < 1440){ h=b/180; m=b%180; nm=180; nk=64; periodic=1; coord=lon; freqs=flong; W=wlong; out=modul; }
  else        { int b2=b-1440; h=b2/91; m=b2%91; nm=91; nk=32; periodic=0; coord=lat; freqs=flat; W=wlatm; out=modua; }
  __shared__ float basis[64];
  float dist = fabsf(coord[m] - coord[0]);
  if(periodic && dist > PI_F) dist = 2.f*PI_F - dist;
  float d = dist + 1e-5f;
  if(t < nk) basis[t] = 0.7978845608028654f * sinf(freqs[t]*d/PI_F) / d;
  __syncthreads();
  if(t < 192){
    float s=0.f;
    for(int k=0;k<nk;k++) s += basis[k]*W[(size_t)(k*8+h)*192+t];
    out[((size_t)h*192 + t)*nm + m] = s;
  }
}

// ---------------- merged low-rank kernels (coalesced d-major loads) -> padded bf16 ----------------
__global__ __launch_bounds__(256) void lrk2_k(const float* __restrict__ qlong,
                                              const float* __restrict__ qlat,
                                              const float* __restrict__ klkl,
                                              const float* __restrict__ klka,
                                              const float* __restrict__ modul,
                                              const float* __restrict__ modua,
                                              const float* __restrict__ wlat,
                                              __bf16* __restrict__ kbg,
                                              __bf16* __restrict__ kbl){
  int b = blockIdx.x, t = threadIdx.x;
  const float* qry; const float* kt; const float* mt; const float* js; __bf16* out;
  int h, i, n, pitch; float scale;
  if(b < 1440){ h=b/180; i=b%180; n=180; pitch=192; qry=qlong; kt=klkl; mt=modul; js=nullptr; out=kbg; scale=2.f*PI_F/180.f; }
  else        { int b2=b-1440; h=b2/91; i=b2%91; n=91; pitch=96; qry=qlat; kt=klka; mt=modua; js=wlat; out=kbl; scale=PI_F/91.f; }
  __shared__ float qs[192];
  if(t<192) qs[t] = qry[(size_t)i*1536 + h*192 + t];
  __syncthreads();
  int j = t;
  if(j < n){
    int m = abs(i-j);
    const float* kp = kt + (size_t)h*192*n;
    const float* mp = mt + (size_t)h*192*n;
    float s=0.f;
    #pragma unroll 4
    for(int d=0;d<192;d++) s += qs[d] * kp[(size_t)d*n + j] * mp[(size_t)d*n + m];
    s = (s>=0.f) ? s : 0.2f*s;
    if(js) s *= js[j];
    out[((size_t)h*pitch + i)*pitch + j] = (__bf16)(s*scale);
  }
}

// ---------------- apply1 MFMA: per (h,m): C[91,64] = klat[h](91x91) @ V(91x64) ----------------
// Epilogue staged through vst (reused as [91][72] bf16) -> 128B vector row stores.
__global__ __launch_bounds__(256) void apply1_mfma(const __bf16* __restrict__ Kl,
                                                   const __bf16* __restrict__ vbf,
                                                   __bf16* __restrict__ u1){
  int h = blockIdx.x / 180, m = blockIdx.x % 180;
  __shared__ __bf16 vst[64][104];           // 6656 elems; reused as ost[91][72]=6552
  int t = threadIdx.x;
  const __bf16* src = vbf + ((size_t)(h*180+m)*91)*64;
  for(int idx=t; idx<91*64; idx+=256){
    int j = idx>>6, c = idx&63;
    vst[c][j] = src[idx];
  }
  for(int idx=t; idx<64*13; idx+=256){
    int c = idx/13, j = 91 + idx - (idx/13)*13;
    vst[c][j] = (__bf16)0.f;
  }
  __syncthreads();
  int lane = t & 63, wave = t>>6;
  int m16 = lane & 15, quad = lane>>4;
  floatx4 acc[6];
  #pragma unroll
  for(int i=0;i<6;i++) acc[i]=(floatx4)0.f;
  const __bf16* Ab = Kl + (size_t)h*96*96;
  #pragma unroll
  for(int kc=0; kc<3; kc++){
    bf16x8 bfrag = *(const bf16x8*)&vst[wave*16 + m16][kc*32 + quad*8];
    #pragma unroll
    for(int ti=0;ti<6;ti++){
      bf16x8 afrag = *(const bf16x8*)&Ab[(size_t)(ti*16+m16)*96 + kc*32 + quad*8];
      acc[ti] = __builtin_amdgcn_mfma_f32_16x16x32_bf16(afrag, bfrag, acc[ti], 0,0,0);
    }
  }
  __syncthreads();                          // vst reads done; reuse as ost
  __bf16* ost = &vst[0][0];
  int c = wave*16 + m16;
  #pragma unroll
  for(int ti=0;ti<6;ti++){
    #pragma unroll
    for(int reg=0;reg<4;reg++){
      int i = ti*16 + quad*4 + reg;
      if(i<91) ost[i*72 + c] = (__bf16)acc[ti][reg];
    }
  }
  __syncthreads();
  __bf16* dst = u1 + (((size_t)(h*91)*180)+m)*64;
  for(int idx=t; idx<91*8; idx+=256){
    int i = idx>>3, cc = idx&7;
    *(bf16x8*)(dst + (size_t)i*180*64 + cc*8) = *(const bf16x8*)&ost[i*72 + cc*8];
  }
}

// ---------------- apply2 MFMA: A2 bf16 [pos][512] via staged 128B stores + GN2 partials ----------------
__global__ __launch_bounds__(256) void apply2_mfma(const __bf16* __restrict__ Kg,
                                                   const __bf16* __restrict__ u1,
                                                   __bf16* __restrict__ a2,
                                                   float* __restrict__ part2){
  int h = blockIdx.x / 91, i = blockIdx.x % 91;
  __shared__ __bf16 vst[64][208];           // 13312 elems; reused as ost[180][72]=12960
  __shared__ float rs[256], rq[256];
  int t = threadIdx.x;
  const __bf16* src = u1 + ((size_t)(h*91+i)*180)*64;
  for(int idx=t; idx<180*64; idx+=256){
    int m = idx>>6, c = idx&63;
    vst[c][m] = src[idx];
  }
  for(int idx=t; idx<64*28; idx+=256){
    int c = idx/28, m = 180 + idx - (idx/28)*28;
    vst[c][m] = (__bf16)0.f;
  }
  __syncthreads();
  int lane = t&63, wave = t>>6;
  int m16 = lane&15, quad = lane>>4;
  floatx4 acc[12];
  #pragma unroll
  for(int l=0;l<12;l++) acc[l]=(floatx4)0.f;
  const __bf16* Ab = Kg + (size_t)h*192*192;
  for(int kc=0; kc<6; kc++){
    bf16x8 bfrag = *(const bf16x8*)&vst[wave*16+m16][kc*32 + quad*8];
    #pragma unroll
    for(int tl=0; tl<12; tl++){
      bf16x8 afrag = *(const bf16x8*)&Ab[(size_t)(tl*16+m16)*192 + kc*32 + quad*8];
      acc[tl] = __builtin_amdgcn_mfma_f32_16x16x32_bf16(afrag, bfrag, acc[tl], 0,0,0);
    }
  }
  __syncthreads();                          // vst reads done; reuse as ost
  __bf16* ost = &vst[0][0];
  int c = wave*16+m16;
  float s=0.f, q=0.f;
  #pragma unroll
  for(int tl=0; tl<12; tl++){
    #pragma unroll
    for(int reg=0; reg<4; reg++){
      int l = tl*16 + quad*4 + reg;
      if(l<180){
        float v = acc[tl][reg];
        ost[l*72 + c] = (__bf16)v;
        s += v; q += v*v;
      }
    }
  }
  rs[t]=s; rq[t]=q;
  __syncthreads();
  for(int st=128; st>0; st>>=1){ if(t<st){ rs[t]+=rs[t+st]; rq[t]+=rq[t+st]; } __syncthreads(); }
  if(t==0){ part2[blockIdx.x*2+0]=rs[0]; part2[blockIdx.x*2+1]=rq[0]; }
  __bf16* dst = a2 + (size_t)i*180*512 + h*64;
  for(int idx=t; idx<180*8; idx+=256){
    int l = idx>>3, cc = idx&7;
    *(bf16x8*)(dst + (size_t)l*512 + cc*8) = *(const bf16x8*)&ost[l*72 + cc*8];
  }
}

// ---------------------------------------------------------------------------
extern "C" void kernel_launch(void* const* d_in, const int* in_sizes, int n_in,
                              void* d_out, int out_size, void* d_ws, size_t ws_size,
                              hipStream_t stream){
  const float* u_src      = (const float*)d_in[0];
  const float* u_lat_qry  = (const float*)d_in[1];
  const float* u_long_qry = (const float*)d_in[2];
  const float* lat = (const float*)d_in[3];
  const float* lon = (const float*)((in_sizes[4]==180)? d_in[4] : d_in[5]);
  const float* cm_gn_w = (const float*)d_in[7];
  const float* cm_gn_b = (const float*)d_in[8];
  const float* cm_w1   = (const float*)d_in[9];
  const float* cm_b1   = (const float*)d_in[10];
  const float* cm_w2   = (const float*)d_in[11];
  const float* cm_b2   = (const float*)d_in[12];
  const float* tl_in_w = (const float*)d_in[13];
  const float* tl_ln_w = (const float*)d_in[14];
  const float* tl_ln_b = (const float*)d_in[15];
  const float* tl_w1   = (const float*)d_in[16];
  const float* tl_b1   = (const float*)d_in[17];
  const float* tl_w2   = (const float*)d_in[18];
  const float* tl_b2   = (const float*)d_in[19];
  const float* ta_in_w = (const float*)d_in[20];
  const float* ta_ln_w = (const float*)d_in[21];
  const float* ta_ln_b = (const float*)d_in[22];
  const float* ta_w1   = (const float*)d_in[23];
  const float* ta_b1   = (const float*)d_in[24];
  const float* ta_w2   = (const float*)d_in[25];
  const float* ta_b2   = (const float*)d_in[26];
  const float* klong_wk= (const float*)d_in[27];
  const float* klat_wk = (const float*)d_in[28];
  const float* pe_long_freq = (const float*)d_in[29];
  const float* pe_long_w    = (const float*)d_in[30];
  const float* pe_lat_freq  = (const float*)d_in[31];
  const float* pe_lat_w     = (const float*)d_in[32];
  const float* mh_gn_w = (const float*)d_in[33];
  const float* mh_gn_b = (const float*)d_in[34];
  const float* mh_w    = (const float*)d_in[35];

  float* ws = (float*)d_ws;
  const size_t OFF_PART1  = 0;          // 32768
  const size_t OFF_GN1    = 32768;      // 64
  const size_t OFF_WLAT   = 32896;      // 91
  const size_t OFF_ULSRC  = 33024;      // 46080
  const size_t OFF_UASRC  = 79104;      // 23296
  const size_t OFF_KLKL   = 102400;     // 276480 fp32 kprojT long [1536][180]
  const size_t OFF_KLKA   = 378880;     // 139776 fp32 kprojT lat  [1536][91]
  const size_t OFF_MODUL  = 518656;     // 276480 fp32 modT long [1536][180]
  const size_t OFF_MODUA  = 795136;     // 139776 fp32 modT lat  [1536][91]
  const size_t OFF_KBL    = 934912;     // bf16 8*96*96   -> 36864 f
  const size_t OFF_KBG    = 971776;     // bf16 8*192*192 -> 147456 f -> ends 1119232
  const size_t OFF_PART2  = 1119232;    // 1456
  const size_t OFF_B1P    = 1120688;    // 1024
  const size_t OFF_B3     = 1121712;    // 256
  const size_t OFF_WT1    = 1122048;    // bf16 [1024][256] -> 131072 f
  const size_t OFF_WT2    = 1253120;    // bf16 [768][1024] -> 393216 f
  const size_t OFF_WT3    = 1646336;    // bf16 [256][512]  -> 65536 f -> ends 1711872
  const size_t OFF_VBF    = 1711872;    // bf16 [8][180][91][64] -> 4193280 f
  const size_t OFF_A2     = 1711872;    // bf16 [16380][512] (reuses VBF post-apply1)
  const size_t OFF_UMID   = 5905152;    // bf16 [16380][256] -> 2096640 f
  const size_t OFF_H1     = 8001792;    // bf16 16380x1024 -> 8386560 f
  const size_t OFF_U1     = 8001792;    // bf16 (reuses H1)
  const size_t OFF_A1     = 16388352;   // bf16 16380x256 -> ends 18484992 (~74 MB)

  const int NPOS = 16380;

  // 1) prep (zfill + wcvt w2 + wlat)
  prep_k<<<4513,256,0,stream>>>(cm_w2, (__bf16*)(ws+OFF_WT2), (__bf16*)(ws+OFF_KBL),
      lat, ws+OFF_WLAT);

  // 2) GN1 partials + bf16 cast of u_src, parallel final reduce
  gn1cast_k<<<512,256,0,stream>>>(u_src, (__bf16*)(ws+OFF_A1), ws+OFF_PART1, NPOS);
  gn_final_par<<<1,256,0,stream>>>(ws+OFF_PART1, ws+OFF_GN1, 512, 1.f/131040.f);

  // 3) fold GN1 into W1
  w1fix_k<<<1024,256,0,stream>>>(cm_w1, cm_b1, ws+OFF_GN1, cm_gn_w, cm_gn_b,
      (__bf16*)(ws+OFF_WT1), ws+OFF_B1P);

  // 4) h1 = gelu(A1 @ W1' + b1')  [16380 x 1024] bf16
  gemm_ld<1,1><<<dim3(128,8),256,0,stream>>>((const __bf16*)(ws+OFF_A1),
      (const __bf16*)(ws+OFF_WT1), ws+OFF_B1P, ws+OFF_H1, nullptr, nullptr, NPOS, 1024, 256);

  // 5) u2 = h1 @ W2 + b2: cols<512 -> vbf bf16; cols>=512 -> umid bf16
  gemm_ld<0,2><<<dim3(128,6),256,0,stream>>>((const __bf16*)(ws+OFF_H1),
      (const __bf16*)(ws+OFF_WT2), cm_b2, nullptr, (__bf16*)(ws+OFF_VBF),
      (__bf16*)(ws+OFF_UMID), NPOS, 768, 1024);

  // 6) merged mean + pooling MLPs
  mpool_k<<<271,256,0,stream>>>((const __bf16*)(ws+OFF_UMID), ws+OFF_WLAT,
      tl_in_w, tl_ln_w, tl_ln_b, tl_w1, tl_b1, tl_w2, tl_b2,
      ta_in_w, ta_ln_w, ta_ln_b, ta_w1, ta_b1, ta_w2, ta_b2,
      ws+OFF_ULSRC, ws+OFF_UASRC);

  // 7) merged k-projections (transposed)
  rowmmT2_k<<<dim3(271,6),256,0,stream>>>(ws+OFF_ULSRC, ws+OFF_UASRC, klong_wk, klat_wk,
      ws+OFF_KLKL, ws+OFF_KLKA);

  // 8) merged modulation tables (transposed)
  modu2_k<<<2168,256,0,stream>>>(lon, lat, pe_long_freq, pe_lat_freq, pe_long_w, pe_lat_w,
      ws+OFF_MODUL, ws+OFF_MODUA);

  // 9) merged low-rank kernels -> padded bf16
  lrk2_k<<<2168,256,0,stream>>>(u_long_qry, u_lat_qry, ws+OFF_KLKL, ws+OFF_KLKA,
      ws+OFF_MODUL, ws+OFF_MODUA, ws+OFF_WLAT, (__bf16*)(ws+OFF_KBG), (__bf16*)(ws+OFF_KBL));

  // 10) kernel application (MFMA, vectorized epilogues); apply2 emits A2 + GN2 partials
  apply1_mfma<<<8*180,256,0,stream>>>((const __bf16*)(ws+OFF_KBL), (const __bf16*)(ws+OFF_VBF),
      (__bf16*)(ws+OFF_U1));
  apply2_mfma<<<8*91, 256,0,stream>>>((const __bf16*)(ws+OFF_KBG), (const __bf16*)(ws+OFF_U1),
      (__bf16*)(ws+OFF_A2), ws+OFF_PART2);

  // 11) fold GN2 into mh_w, then final projection
  w3fix_k<<<256,256,0,stream>>>(mh_w, ws+OFF_PART2, mh_gn_w, mh_gn_b,
      (__bf16*)(ws+OFF_WT3), ws+OFF_B3);
  gemm_ld<0,0><<<dim3(128,2),256,0,stream>>>((const __bf16*)(ws+OFF_A2),
      (const __bf16*)(ws+OFF_WT3), ws+OFF_B3, (float*)d_out, nullptr, nullptr, NPOS, 256, 512);
}

// Round 9
// 442.905 us; speedup vs baseline: 1.0272x; 1.0272x over previous
//
#include <hip/hip_runtime.h>
#include <math.h>

#define PI_F 3.14159265358979323846f

typedef __bf16  bf16x8  __attribute__((ext_vector_type(8)));
typedef float   floatx4 __attribute__((ext_vector_type(4)));

__device__ __forceinline__ float gelu_tanh(float x){
  float x3 = x*x*x;
  float t = tanhf(0.7978845608028654f*(x + 0.044715f*x3));
  return 0.5f*x*(1.0f+t);
}

// async global->LDS 16B per lane; LDS dest = wave-uniform base + lane*16
__device__ __forceinline__ void gl_lds16(const void* g, void* l){
  __builtin_amdgcn_global_load_lds(
      (const __attribute__((address_space(1))) void*)(uintptr_t)g,
      (__attribute__((address_space(3))) void*)(uintptr_t)l,
      16, 0, 0);
}

// ---------------- prep: zfill K buffers + wcvt cm_w2 + wlat (one dispatch) ----------------
__global__ __launch_bounds__(256) void prep_k(const float* __restrict__ w2in,
                                              __bf16* __restrict__ wt2,
                                              __bf16* __restrict__ kbuf,
                                              const float* __restrict__ lat,
                                              float* __restrict__ wlat){
  int b = blockIdx.x, t = threadIdx.x;
  if(b < 1440){
    int i = b*256 + t;
    if(i < 368640) kbuf[i] = (__bf16)0.f;
  } else if(b < 4512){
    int idx = (b-1440)*256 + t;   // 786432 total
    int n = idx >> 10, k = idx & 1023;      // wt2[n][k] = w2[k][n], N=768,K=1024
    wt2[idx] = (__bf16)w2in[(size_t)k*768 + n];
  } else {
    if(t < 91) wlat[t] = cosf(lat[t]);
    __syncthreads();
    if(t == 0){
      float dlat = lat[1]-lat[0];
      float s4 = sinf(dlat*0.25f);
      float pw = s4*s4 / sinf(dlat*0.5f);
      if(wlat[0]  < 0.001f) wlat[0]  = pw;
      if(wlat[90] < 0.001f) wlat[90] = pw;
    }
  }
}

// ---------------- GN1 partial stats + plain bf16 cast of u_src (512 blocks) ----------------
__global__ __launch_bounds__(256) void gn1cast_k(const float* __restrict__ x,
                                                 __bf16* __restrict__ xa,
                                                 float* __restrict__ part, int npos){
  int c = threadIdx.x;
  float s=0.f, q=0.f;
  for(int p=blockIdx.x; p<npos; p+=gridDim.x){
    float v = x[p*256 + c];
    xa[p*256 + c] = (__bf16)v;
    s += v; q += v*v;
  }
  __shared__ float ss[256], sq[256];
  ss[c]=s; sq[c]=q;
  __syncthreads();
  if((c&7)==0){
    float a=0.f,b=0.f;
    #pragma unroll
    for(int k=0;k<8;k++){ a+=ss[c+k]; b+=sq[c+k]; }
    int g=c>>3;
    part[(blockIdx.x*32+g)*2+0]=a;
    part[(blockIdx.x*32+g)*2+1]=b;
  }
}

// ---------------- parallel GN final reduce ----------------
__global__ __launch_bounds__(256) void gn_final_par(const float* __restrict__ part,
                                                    float* __restrict__ stats,
                                                    int nblk, float invN){
  int t = threadIdx.x;
  int g = t & 31, ch = t >> 5;       // 8 chunks
  float s=0.f,q=0.f;
  for(int b=ch; b<nblk; b+=8){
    s += part[(b*32+g)*2+0];
    q += part[(b*32+g)*2+1];
  }
  __shared__ float ss[256], sq[256];
  ss[t]=s; sq[t]=q;
  __syncthreads();
  if(t<32){
    float a=0.f,bq=0.f;
    #pragma unroll
    for(int c=0;c<8;c++){ a+=ss[c*32+t]; bq+=sq[c*32+t]; }
    float m = a*invN;
    float v = bq*invN - m*m;
    stats[t*2+0]=m;
    stats[t*2+1]=rsqrtf(v+1e-5f);
  }
}

// ---------------- fold GN1 into W1 ----------------
__global__ __launch_bounds__(256) void w1fix_k(const float* __restrict__ w1,
                                               const float* __restrict__ b1,
                                               const float* __restrict__ stats,
                                               const float* __restrict__ gw,
                                               const float* __restrict__ gb,
                                               __bf16* __restrict__ wt1,
                                               float* __restrict__ b1p){
  int n = blockIdx.x, c = threadIdx.x;
  int g = c>>3;
  float m = stats[g*2+0], r = stats[g*2+1];
  float s = r*gw[c];
  float t = gb[c] - m*s;
  float w = w1[(size_t)c*1024 + n];
  wt1[(size_t)n*256 + c] = (__bf16)(s*w);
  __shared__ float red[256];
  red[c] = t*w; __syncthreads();
  for(int st=128; st>0; st>>=1){ if(c<st) red[c]+=red[c+st]; __syncthreads(); }
  if(c==0) b1p[n] = b1[n] + red[0];
}

// ---------------- fold GN2 into mh_w ----------------
__global__ __launch_bounds__(256) void w3fix_k(const float* __restrict__ mhw,
                                               const float* __restrict__ part2,
                                               const float* __restrict__ gw,
                                               const float* __restrict__ gb,
                                               __bf16* __restrict__ wt3,
                                               float* __restrict__ b3){
  __shared__ float st[16];
  __shared__ float ps[256], pq[256];
  int n = blockIdx.x, t = threadIdx.x;
  {
    int g = t & 7, ch = t >> 3;
    float s=0.f,q=0.f;
    for(int i=ch; i<91; i+=32){
      s += part2[(g*91+i)*2+0];
      q += part2[(g*91+i)*2+1];
    }
    ps[t]=s; pq[t]=q;
    __syncthreads();
    if(t<8){
      float a=0.f,bq=0.f;
      #pragma unroll
      for(int c=0;c<32;c++){ a+=ps[c*8+t]; bq+=pq[c*8+t]; }
      float m = a*(1.f/1048320.f);
      float v = bq*(1.f/1048320.f) - m*m;
      st[t*2+0]=m; st[t*2+1]=rsqrtf(v+1e-5f);
    }
    __syncthreads();
  }
  float bp=0.f;
  #pragma unroll
  for(int l=0;l<2;l++){
    int cc = t + l*256;
    int g = cc>>6;
    float m = st[g*2+0], r = st[g*2+1];
    float s = r*gw[cc];
    float tt = gb[cc] - m*s;
    float w = mhw[(size_t)cc*256 + n];
    wt3[(size_t)n*512 + cc] = (__bf16)(s*w);
    bp += tt*w;
  }
  __shared__ float red[256];
  red[t]=bp; __syncthreads();
  for(int stp=128;stp>0;stp>>=1){ if(t<stp) red[t]+=red[t+stp]; __syncthreads(); }
  if(t==0) b3[n]=red[0];
}

// ---------------- MFMA bf16 GEMM: BK=32, global_load_lds staging + XOR-swizzled LDS ----------------
// (Round-7 structure: 16KB LDS, 72 VGPR, ~26% occupancy — BK=64 regressed via occupancy, R8.)
// Grid (row-fastest): all col-blocks of an A-row-tile share one XCD -> A fetched once/XCD.
// Swizzle: 16B chunk c of LDS row r stored at phys chunk c ^ ((r>>1)&3) -> 2-way banks (free).
// OUTMODE: 0 = fp32 C, 1 = bf16 C, 2 = u2-split (cols<512 -> VB bf16 [h][m][j][c]; cols>=512 -> UM bf16 [pos][256])
template<int ACT, int OUTMODE>
__global__ __launch_bounds__(256) void gemm_ld(const __bf16* __restrict__ A,
                                               const __bf16* __restrict__ Bt,
                                               const float* __restrict__ bias,
                                               void* __restrict__ Cp,
                                               __bf16* __restrict__ VB,
                                               __bf16* __restrict__ UM,
                                               int M, int N, int K)
{
  __shared__ __bf16 As[128][32];
  __shared__ __bf16 Bs[128][32];
  const int tid  = threadIdx.x;
  const int lane = tid & 63, wave = tid >> 6;
  const int row0 = blockIdx.x*128, col0 = blockIdx.y*128;
  const int lrow = lane >> 2;                       // 16 rows per wave-load
  const int csw  = ((lane&3) ^ ((lane>>3)&3)) * 8;  // swizzled source chunk
  const int wr = (wave >> 1)*64, wc = (wave & 1)*64;
  const int m16 = lane & 15, quad = lane >> 4;
  const int pa = (quad ^ ((m16>>1)&3)) * 8;         // swizzled read chunk

  const __bf16* Ag0 = A  + (size_t)(row0 + wave*32 + lrow)*K + csw;
  const __bf16* Ag1 = Ag0 + (size_t)16*K;
  const __bf16* Bg0 = Bt + (size_t)(col0 + wave*32 + lrow)*K + csw;
  const __bf16* Bg1 = Bg0 + (size_t)16*K;
  void* la0 = &As[wave*32     ][0];
  void* la1 = &As[wave*32 + 16][0];
  void* lb0 = &Bs[wave*32     ][0];
  void* lb1 = &Bs[wave*32 + 16][0];

  floatx4 acc[4][4];
  #pragma unroll
  for(int i=0;i<4;i++)
    #pragma unroll
    for(int j=0;j<4;j++) acc[i][j] = (floatx4)0.f;

  const int kiters = K >> 5;
  for(int kk=0; kk<kiters; kk++){
    __syncthreads();
    gl_lds16(Ag0, la0);
    gl_lds16(Ag1, la1);
    gl_lds16(Bg0, lb0);
    gl_lds16(Bg1, lb1);
    Ag0 += 32; Ag1 += 32; Bg0 += 32; Bg1 += 32;
    __syncthreads();

    bf16x8 af[4], bfv[4];
    #pragma unroll
    for(int ti=0;ti<4;ti++) af[ti]  = *(const bf16x8*)&As[wr + ti*16 + m16][pa];
    #pragma unroll
    for(int tj=0;tj<4;tj++) bfv[tj] = *(const bf16x8*)&Bs[wc + tj*16 + m16][pa];
    #pragma unroll
    for(int ti=0;ti<4;ti++)
      #pragma unroll
      for(int tj=0;tj<4;tj++)
        acc[ti][tj] = __builtin_amdgcn_mfma_f32_16x16x32_bf16(af[ti], bfv[tj], acc[ti][tj], 0,0,0);
  }

  #pragma unroll
  for(int ti=0;ti<4;ti++){
    #pragma unroll
    for(int reg=0;reg<4;reg++){
      int gr = row0 + wr + ti*16 + quad*4 + reg;
      if(gr >= M) continue;
      int jj = gr/180, mm = gr - jj*180;   // only used for OUTMODE 2
      #pragma unroll
      for(int tj=0;tj<4;tj++){
        int gc = col0 + wc + tj*16 + m16;
        float v = acc[ti][tj][reg];
        if(bias) v += bias[gc];
        if(ACT==1) v = gelu_tanh(v);
        if(OUTMODE==2){
          if(gc < 512){
            int hh = gc>>6, cc = gc&63;
            VB[(((size_t)(hh*180+mm)*91)+jj)*64 + cc] = (__bf16)v;
          } else {
            UM[(size_t)gr*256 + (gc-512)] = (__bf16)v;
          }
        } else if(OUTMODE==1){
          ((__bf16*)Cp)[(size_t)gr*N + gc] = (__bf16)v;
        } else {
          ((float*)Cp)[(size_t)gr*N + gc]  = v;
        }
      }
    }
  }
}

// ---------------- merged mean + pooling MLP: one dispatch, 271 blocks ----------------
__device__ __forceinline__ void pool_core(int r, int t, float y,
    const float* __restrict__ lnw, const float* __restrict__ lnb,
    const float* __restrict__ w1, const float* __restrict__ b1,
    const float* __restrict__ w2, const float* __restrict__ b2,
    float* __restrict__ out,
    float* xn, float* red, float* g){
  red[t]=y; __syncthreads();
  for(int s=128;s>0;s>>=1){ if(t<s) red[t]+=red[t+s]; __syncthreads(); }
  float m = red[0]*(1.f/256.f); __syncthreads();
  float d = y-m; red[t]=d*d; __syncthreads();
  for(int s=128;s>0;s>>=1){ if(t<s) red[t]+=red[t+s]; __syncthreads(); }
  float var = red[0]*(1.f/256.f);
  __syncthreads();
  xn[t] = d*rsqrtf(var+1e-5f)*lnw[t]+lnb[t];
  __syncthreads();
  float s1=b1[t], s2=b1[256+t];
  for(int c=0;c<256;c++){ float xv=xn[c]; s1 += xv*w1[c*512+t]; s2 += xv*w1[c*512+256+t]; }
  g[t] = gelu_tanh(s1)*s2;
  __syncthreads();
  float o=b2[t];
  for(int c=0;c<256;c++) o += g[c]*w2[c*256+t];
  out[r*256+t]=o;
}

__global__ __launch_bounds__(256) void mpool_k(
    const __bf16* __restrict__ um, const float* __restrict__ wlat,
    const float* __restrict__ tl_inw, const float* __restrict__ tl_lnw, const float* __restrict__ tl_lnb,
    const float* __restrict__ tl_w1, const float* __restrict__ tl_b1,
    const float* __restrict__ tl_w2, const float* __restrict__ tl_b2,
    const float* __restrict__ ta_inw, const float* __restrict__ ta_lnw, const float* __restrict__ ta_lnb,
    const float* __restrict__ ta_w1, const float* __restrict__ ta_b1,
    const float* __restrict__ ta_w2, const float* __restrict__ ta_b2,
    float* __restrict__ ulsrc, float* __restrict__ uasrc){
  __shared__ float xs[256], xn[256], red[256], g[256];
  int b = blockIdx.x, t = threadIdx.x;
  if(b < 180){
    float s=0.f;
    for(int j=0;j<91;j++) s += (float)um[(size_t)(j*180+b)*256 + t];
    xs[t] = s*(1.0f/91.0f);
    __syncthreads();
    float y=0.f;
    for(int c=0;c<256;c++) y += xs[c]*tl_inw[c*256+t];
    pool_core(b, t, y, tl_lnw, tl_lnb, tl_w1, tl_b1, tl_w2, tl_b2, ulsrc, xn, red, g);
  } else {
    int r = b-180;
    const __bf16* base = um + (size_t)r*180*256 + t;
    float s=0.f;
    for(int m=0;m<180;m++) s += (float)base[(size_t)m*256];
    xs[t] = s*(1.0f/180.0f);
    __syncthreads();
    float y=0.f;
    for(int c=0;c<256;c++) y += xs[c]*ta_inw[c*256+t];
    y *= wlat[r];
    pool_core(r, t, y, ta_lnw, ta_lnb, ta_w1, ta_b1, ta_w2, ta_b2, uasrc, xn, red, g);
  }
}

// ---------------- merged k-projection, transposed output out[col][r] ----------------
__global__ __launch_bounds__(256) void rowmmT2_k(const float* __restrict__ ulsrc,
                                                 const float* __restrict__ uasrc,
                                                 const float* __restrict__ wlong,
                                                 const float* __restrict__ wlatk,
                                                 float* __restrict__ klkl,
                                                 float* __restrict__ klka){
  int b = blockIdx.x, t = threadIdx.x;
  const float* X; const float* W; float* out; int r, R;
  if(b < 180){ r=b;     X=ulsrc; W=wlong; out=klkl; R=180; }
  else       { r=b-180; X=uasrc; W=wlatk; out=klka; R=91;  }
  int j = blockIdx.y*256 + t;
  __shared__ float xs[256];
  xs[t] = X[r*256 + t];
  __syncthreads();
  float s = 0.f;
  for(int c=0;c<256;c++) s += xs[c]*W[(size_t)c*1536 + j];
  out[(size_t)j*R + r] = s;
}

// ---------------- merged modulation tables, transposed out[(h*192+d)][m] ----------------
__global__ __launch_bounds__(256) void modu2_k(const float* __restrict__ lon,
                                               const float* __restrict__ lat,
                                               const float* __restrict__ flong,
                                               const float* __restrict__ flat,
                                               const float* __restrict__ wlong,
                                               const float* __restrict__ wlatm,
                                               float* __restrict__ modul,
                                               float* __restrict__ modua){
  int b = blockIdx.x, t = threadIdx.x;
  const float* coord; const float* freqs; const float* W; float* out;
  int h, m, nm, nk, periodic;
  if(b < 1440){ h=b/180; m=b%180; nm=180; nk=64; periodic=1; coord=lon; freqs=flong; W=wlong; out=modul; }
  else        { int b2=b-1440; h=b2/91; m=b2%91; nm=91; nk=32; periodic=0; coord=lat; freqs=flat; W=wlatm; out=modua; }
  __shared__ float basis[64];
  float dist = fabsf(coord[m] - coord[0]);
  if(periodic && dist > PI_F) dist = 2.f*PI_F - dist;
  float d = dist + 1e-5f;
  if(t < nk) basis[t] = 0.7978845608028654f * sinf(freqs[t]*d/PI_F) / d;
  __syncthreads();
  if(t < 192){
    float s=0.f;
    for(int k=0;k<nk;k++) s += basis[k]*W[(size_t)(k*8+h)*192+t];
    out[((size_t)h*192 + t)*nm + m] = s;
  }
}

// ---------------- merged low-rank kernels (coalesced d-major loads) -> padded bf16 ----------------
__global__ __launch_bounds__(256) void lrk2_k(const float* __restrict__ qlong,
                                              const float* __restrict__ qlat,
                                              const float* __restrict__ klkl,
                                              const float* __restrict__ klka,
                                              const float* __restrict__ modul,
                                              const float* __restrict__ modua,
                                              const float* __restrict__ wlat,
                                              __bf16* __restrict__ kbg,
                                              __bf16* __restrict__ kbl){
  int b = blockIdx.x, t = threadIdx.x;
  const float* qry; const float* kt; const float* mt; const float* js; __bf16* out;
  int h, i, n, pitch; float scale;
  if(b < 1440){ h=b/180; i=b%180; n=180; pitch=192; qry=qlong; kt=klkl; mt=modul; js=nullptr; out=kbg; scale=2.f*PI_F/180.f; }
  else        { int b2=b-1440; h=b2/91; i=b2%91; n=91; pitch=96; qry=qlat; kt=klka; mt=modua; js=wlat; out=kbl; scale=PI_F/91.f; }
  __shared__ float qs[192];
  if(t<192) qs[t] = qry[(size_t)i*1536 + h*192 + t];
  __syncthreads();
  int j = t;
  if(j < n){
    int m = abs(i-j);
    const float* kp = kt + (size_t)h*192*n;
    const float* mp = mt + (size_t)h*192*n;
    float s=0.f;
    #pragma unroll 4
    for(int d=0;d<192;d++) s += qs[d] * kp[(size_t)d*n + j] * mp[(size_t)d*n + m];
    s = (s>=0.f) ? s : 0.2f*s;
    if(js) s *= js[j];
    out[((size_t)h*pitch + i)*pitch + j] = (__bf16)(s*scale);
  }
}

// ---------------- apply1 MFMA: per (h,m): C[91,64] = klat[h](91x91) @ V(91x64) ----------------
// Epilogue staged through vst (reused as [91][72] bf16) -> 128B vector row stores.
__global__ __launch_bounds__(256) void apply1_mfma(const __bf16* __restrict__ Kl,
                                                   const __bf16* __restrict__ vbf,
                                                   __bf16* __restrict__ u1){
  int h = blockIdx.x / 180, m = blockIdx.x % 180;
  __shared__ __bf16 vst[64][104];           // 6656 elems; reused as ost[91][72]=6552
  int t = threadIdx.x;
  const __bf16* src = vbf + ((size_t)(h*180+m)*91)*64;
  for(int idx=t; idx<91*64; idx+=256){
    int j = idx>>6, c = idx&63;
    vst[c][j] = src[idx];
  }
  for(int idx=t; idx<64*13; idx+=256){
    int c = idx/13, j = 91 + idx - (idx/13)*13;
    vst[c][j] = (__bf16)0.f;
  }
  __syncthreads();
  int lane = t & 63, wave = t>>6;
  int m16 = lane & 15, quad = lane>>4;
  floatx4 acc[6];
  #pragma unroll
  for(int i=0;i<6;i++) acc[i]=(floatx4)0.f;
  const __bf16* Ab = Kl + (size_t)h*96*96;
  #pragma unroll
  for(int kc=0; kc<3; kc++){
    bf16x8 bfrag = *(const bf16x8*)&vst[wave*16 + m16][kc*32 + quad*8];
    #pragma unroll
    for(int ti=0;ti<6;ti++){
      bf16x8 afrag = *(const bf16x8*)&Ab[(size_t)(ti*16+m16)*96 + kc*32 + quad*8];
      acc[ti] = __builtin_amdgcn_mfma_f32_16x16x32_bf16(afrag, bfrag, acc[ti], 0,0,0);
    }
  }
  __syncthreads();                          // vst reads done; reuse as ost
  __bf16* ost = &vst[0][0];
  int c = wave*16 + m16;
  #pragma unroll
  for(int ti=0;ti<6;ti++){
    #pragma unroll
    for(int reg=0;reg<4;reg++){
      int i = ti*16 + quad*4 + reg;
      if(i<91) ost[i*72 + c] = (__bf16)acc[ti][reg];
    }
  }
  __syncthreads();
  __bf16* dst = u1 + (((size_t)(h*91)*180)+m)*64;
  for(int idx=t; idx<91*8; idx+=256){
    int i = idx>>3, cc = idx&7;
    *(bf16x8*)(dst + (size_t)i*180*64 + cc*8) = *(const bf16x8*)&ost[i*72 + cc*8];
  }
}

// ---------------- apply2 MFMA: A2 bf16 [pos][512] via staged 128B stores + GN2 partials ----------------
__global__ __launch_bounds__(256) void apply2_mfma(const __bf16* __restrict__ Kg,
                                                   const __bf16* __restrict__ u1,
                                                   __bf16* __restrict__ a2,
                                                   float* __restrict__ part2){
  int h = blockIdx.x / 91, i = blockIdx.x % 91;
  __shared__ __bf16 vst[64][208];           // 13312 elems; reused as ost[180][72]=12960
  __shared__ float rs[256], rq[256];
  int t = threadIdx.x;
  const __bf16* src = u1 + ((size_t)(h*91+i)*180)*64;
  for(int idx=t; idx<180*64; idx+=256){
    int m = idx>>6, c = idx&63;
    vst[c][m] = src[idx];
  }
  for(int idx=t; idx<64*28; idx+=256){
    int c = idx/28, m = 180 + idx - (idx/28)*28;
    vst[c][m] = (__bf16)0.f;
  }
  __syncthreads();
  int lane = t&63, wave = t>>6;
  int m16 = lane&15, quad = lane>>4;
  floatx4 acc[12];
  #pragma unroll
  for(int l=0;l<12;l++) acc[l]=(floatx4)0.f;
  const __bf16* Ab = Kg + (size_t)h*192*192;
  for(int kc=0; kc<6; kc++){
    bf16x8 bfrag = *(const bf16x8*)&vst[wave*16+m16][kc*32 + quad*8];
    #pragma unroll
    for(int tl=0; tl<12; tl++){
      bf16x8 afrag = *(const bf16x8*)&Ab[(size_t)(tl*16+m16)*192 + kc*32 + quad*8];
      acc[tl] = __builtin_amdgcn_mfma_f32_16x16x32_bf16(afrag, bfrag, acc[tl], 0,0,0);
    }
  }
  __syncthreads();                          // vst reads done; reuse as ost
  __bf16* ost = &vst[0][0];
  int c = wave*16+m16;
  float s=0.f, q=0.f;
  #pragma unroll
  for(int tl=0; tl<12; tl++){
    #pragma unroll
    for(int reg=0; reg<4; reg++){
      int l = tl*16 + quad*4 + reg;
      if(l<180){
        float v = acc[tl][reg];
        ost[l*72 + c] = (__bf16)v;
        s += v; q += v*v;
      }
    }
  }
  rs[t]=s; rq[t]=q;
  __syncthreads();
  for(int st=128; st>0; st>>=1){ if(t<st){ rs[t]+=rs[t+st]; rq[t]+=rq[t+st]; } __syncthreads(); }
  if(t==0){ part2[blockIdx.x*2+0]=rs[0]; part2[blockIdx.x*2+1]=rq[0]; }
  __bf16* dst = a2 + (size_t)i*180*512 + h*64;
  for(int idx=t; idx<180*8; idx+=256){
    int l = idx>>3, cc = idx&7;
    *(bf16x8*)(dst + (size_t)l*512 + cc*8) = *(const bf16x8*)&ost[l*72 + cc*8];
  }
}

// ---------------------------------------------------------------------------
extern "C" void kernel_launch(void* const* d_in, const int* in_sizes, int n_in,
                              void* d_out, int out_size, void* d_ws, size_t ws_size,
                              hipStream_t stream){
  const float* u_src      = (const float*)d_in[0];
  const float* u_lat_qry  = (const float*)d_in[1];
  const float* u_long_qry = (const float*)d_in[2];
  const float* lat = (const float*)d_in[3];
  const float* lon = (const float*)((in_sizes[4]==180)? d_in[4] : d_in[5]);
  const float* cm_gn_w = (const float*)d_in[7];
  const float* cm_gn_b = (const float*)d_in[8];
  const float* cm_w1   = (const float*)d_in[9];
  const float* cm_b1   = (const float*)d_in[10];
  const float* cm_w2   = (const float*)d_in[11];
  const float* cm_b2   = (const float*)d_in[12];
  const float* tl_in_w = (const float*)d_in[13];
  const float* tl_ln_w = (const float*)d_in[14];
  const float* tl_ln_b = (const float*)d_in[15];
  const float* tl_w1   = (const float*)d_in[16];
  const float* tl_b1   = (const float*)d_in[17];
  const float* tl_w2   = (const float*)d_in[18];
  const float* tl_b2   = (const float*)d_in[19];
  const float* ta_in_w = (const float*)d_in[20];
  const float* ta_ln_w = (const float*)d_in[21];
  const float* ta_ln_b = (const float*)d_in[22];
  const float* ta_w1   = (const float*)d_in[23];
  const float* ta_b1   = (const float*)d_in[24];
  const float* ta_w2   = (const float*)d_in[25];
  const float* ta_b2   = (const float*)d_in[26];
  const float* klong_wk= (const float*)d_in[27];
  const float* klat_wk = (const float*)d_in[28];
  const float* pe_long_freq = (const float*)d_in[29];
  const float* pe_long_w    = (const float*)d_in[30];
  const float* pe_lat_freq  = (const float*)d_in[31];
  const float* pe_lat_w     = (const float*)d_in[32];
  const float* mh_gn_w = (const float*)d_in[33];
  const float* mh_gn_b = (const float*)d_in[34];
  const float* mh_w    = (const float*)d_in[35];

  float* ws = (float*)d_ws;
  const size_t OFF_PART1  = 0;          // 32768
  const size_t OFF_GN1    = 32768;      // 64
  const size_t OFF_WLAT   = 32896;      // 91
  const size_t OFF_ULSRC  = 33024;      // 46080
  const size_t OFF_UASRC  = 79104;      // 23296
  const size_t OFF_KLKL   = 102400;     // 276480 fp32 kprojT long [1536][180]
  const size_t OFF_KLKA   = 378880;     // 139776 fp32 kprojT lat  [1536][91]
  const size_t OFF_MODUL  = 518656;     // 276480 fp32 modT long [1536][180]
  const size_t OFF_MODUA  = 795136;     // 139776 fp32 modT lat  [1536][91]
  const size_t OFF_KBL    = 934912;     // bf16 8*96*96   -> 36864 f
  const size_t OFF_KBG    = 971776;     // bf16 8*192*192 -> 147456 f -> ends 1119232
  const size_t OFF_PART2  = 1119232;    // 1456
  const size_t OFF_B1P    = 1120688;    // 1024
  const size_t OFF_B3     = 1121712;    // 256
  const size_t OFF_WT1    = 1122048;    // bf16 [1024][256] -> 131072 f
  const size_t OFF_WT2    = 1253120;    // bf16 [768][1024] -> 393216 f
  const size_t OFF_WT3    = 1646336;    // bf16 [256][512]  -> 65536 f -> ends 1711872
  const size_t OFF_VBF    = 1711872;    // bf16 [8][180][91][64] -> 4193280 f
  const size_t OFF_A2     = 1711872;    // bf16 [16380][512] (reuses VBF post-apply1)
  const size_t OFF_UMID   = 5905152;    // bf16 [16380][256] -> 2096640 f
  const size_t OFF_H1     = 8001792;    // bf16 16380x1024 -> 8386560 f
  const size_t OFF_U1     = 8001792;    // bf16 (reuses H1)
  const size_t OFF_A1     = 16388352;   // bf16 16380x256 -> ends 18484992 (~74 MB)

  const int NPOS = 16380;

  // 1) prep (zfill + wcvt w2 + wlat)
  prep_k<<<4513,256,0,stream>>>(cm_w2, (__bf16*)(ws+OFF_WT2), (__bf16*)(ws+OFF_KBL),
      lat, ws+OFF_WLAT);

  // 2) GN1 partials + bf16 cast of u_src, parallel final reduce
  gn1cast_k<<<512,256,0,stream>>>(u_src, (__bf16*)(ws+OFF_A1), ws+OFF_PART1, NPOS);
  gn_final_par<<<1,256,0,stream>>>(ws+OFF_PART1, ws+OFF_GN1, 512, 1.f/131040.f);

  // 3) fold GN1 into W1
  w1fix_k<<<1024,256,0,stream>>>(cm_w1, cm_b1, ws+OFF_GN1, cm_gn_w, cm_gn_b,
      (__bf16*)(ws+OFF_WT1), ws+OFF_B1P);

  // 4) h1 = gelu(A1 @ W1' + b1')  [16380 x 1024] bf16
  gemm_ld<1,1><<<dim3(128,8),256,0,stream>>>((const __bf16*)(ws+OFF_A1),
      (const __bf16*)(ws+OFF_WT1), ws+OFF_B1P, ws+OFF_H1, nullptr, nullptr, NPOS, 1024, 256);

  // 5) u2 = h1 @ W2 + b2: cols<512 -> vbf bf16; cols>=512 -> umid bf16
  gemm_ld<0,2><<<dim3(128,6),256,0,stream>>>((const __bf16*)(ws+OFF_H1),
      (const __bf16*)(ws+OFF_WT2), cm_b2, nullptr, (__bf16*)(ws+OFF_VBF),
      (__bf16*)(ws+OFF_UMID), NPOS, 768, 1024);

  // 6) merged mean + pooling MLPs
  mpool_k<<<271,256,0,stream>>>((const __bf16*)(ws+OFF_UMID), ws+OFF_WLAT,
      tl_in_w, tl_ln_w, tl_ln_b, tl_w1, tl_b1, tl_w2, tl_b2,
      ta_in_w, ta_ln_w, ta_ln_b, ta_w1, ta_b1, ta_w2, ta_b2,
      ws+OFF_ULSRC, ws+OFF_UASRC);

  // 7) merged k-projections (transposed)
  rowmmT2_k<<<dim3(271,6),256,0,stream>>>(ws+OFF_ULSRC, ws+OFF_UASRC, klong_wk, klat_wk,
      ws+OFF_KLKL, ws+OFF_KLKA);

  // 8) merged modulation tables (transposed)
  modu2_k<<<2168,256,0,stream>>>(lon, lat, pe_long_freq, pe_lat_freq, pe_long_w, pe_lat_w,
      ws+OFF_MODUL, ws+OFF_MODUA);

  // 9) merged low-rank kernels -> padded bf16
  lrk2_k<<<2168,256,0,stream>>>(u_long_qry, u_lat_qry, ws+OFF_KLKL, ws+OFF_KLKA,
      ws+OFF_MODUL, ws+OFF_MODUA, ws+OFF_WLAT, (__bf16*)(ws+OFF_KBG), (__bf16*)(ws+OFF_KBL));

  // 10) kernel application (MFMA, vectorized epilogues); apply2 emits A2 + GN2 partials
  apply1_mfma<<<8*180,256,0,stream>>>((const __bf16*)(ws+OFF_KBL), (const __bf16*)(ws+OFF_VBF),
      (__bf16*)(ws+OFF_U1));
  apply2_mfma<<<8*91, 256,0,stream>>>((const __bf16*)(ws+OFF_KBG), (const __bf16*)(ws+OFF_U1),
      (__bf16*)(ws+OFF_A2), ws+OFF_PART2);

  // 11) fold GN2 into mh_w, then final projection
  w3fix_k<<<256,256,0,stream>>>(mh_w, ws+OFF_PART2, mh_gn_w, mh_gn_b,
      (__bf16*)(ws+OFF_WT3), ws+OFF_B3);
  gemm_ld<0,0><<<dim3(128,2),256,0,stream>>>((const __bf16*)(ws+OFF_A2),
      (const __bf16*)(ws+OFF_WT3), ws+OFF_B3, (float*)d_out, nullptr, nullptr, NPOS, 256, 512);
}

// Round 10
// 425.498 us; speedup vs baseline: 1.0692x; 1.0409x over previous
//
#include <hip/hip_runtime.h>
#include <math.h>

#define PI_F 3.14159265358979323846f

typedef __bf16  bf16x8  __attribute__((ext_vector_type(8)));
typedef float   floatx4 __attribute__((ext_vector_type(4)));

__device__ __forceinline__ float gelu_tanh(float x){
  float x3 = x*x*x;
  float t = tanhf(0.7978845608028654f*(x + 0.044715f*x3));
  return 0.5f*x*(1.0f+t);
}

// async global->LDS 16B per lane; LDS dest = wave-uniform base + lane*16
__device__ __forceinline__ void gl_lds16(const void* g, void* l){
  __builtin_amdgcn_global_load_lds(
      (const __attribute__((address_space(1))) void*)(uintptr_t)g,
      (__attribute__((address_space(3))) void*)(uintptr_t)l,
      16, 0, 0);
}

// ---------------- prep: zfill K buffers + wcvt cm_w2 + wlat (one dispatch) ----------------
__global__ __launch_bounds__(256) void prep_k(const float* __restrict__ w2in,
                                              __bf16* __restrict__ wt2,
                                              __bf16* __restrict__ kbuf,
                                              const float* __restrict__ lat,
                                              float* __restrict__ wlat){
  int b = blockIdx.x, t = threadIdx.x;
  if(b < 1440){
    int i = b*256 + t;
    if(i < 368640) kbuf[i] = (__bf16)0.f;
  } else if(b < 4512){
    int idx = (b-1440)*256 + t;   // 786432 total
    int n = idx >> 10, k = idx & 1023;      // wt2[n][k] = w2[k][n], N=768,K=1024
    wt2[idx] = (__bf16)w2in[(size_t)k*768 + n];
  } else {
    if(t < 91) wlat[t] = cosf(lat[t]);
    __syncthreads();
    if(t == 0){
      float dlat = lat[1]-lat[0];
      float s4 = sinf(dlat*0.25f);
      float pw = s4*s4 / sinf(dlat*0.5f);
      if(wlat[0]  < 0.001f) wlat[0]  = pw;
      if(wlat[90] < 0.001f) wlat[90] = pw;
    }
  }
}

// ---------------- GN1 partial stats + plain bf16 cast of u_src (512 blocks) ----------------
__global__ __launch_bounds__(256) void gn1cast_k(const float* __restrict__ x,
                                                 __bf16* __restrict__ xa,
                                                 float* __restrict__ part, int npos){
  int c = threadIdx.x;
  float s=0.f, q=0.f;
  for(int p=blockIdx.x; p<npos; p+=gridDim.x){
    float v = x[p*256 + c];
    xa[p*256 + c] = (__bf16)v;
    s += v; q += v*v;
  }
  __shared__ float ss[256], sq[256];
  ss[c]=s; sq[c]=q;
  __syncthreads();
  if((c&7)==0){
    float a=0.f,b=0.f;
    #pragma unroll
    for(int k=0;k<8;k++){ a+=ss[c+k]; b+=sq[c+k]; }
    int g=c>>3;
    part[(blockIdx.x*32+g)*2+0]=a;
    part[(blockIdx.x*32+g)*2+1]=b;
  }
}

// ---------------- parallel GN final reduce ----------------
__global__ __launch_bounds__(256) void gn_final_par(const float* __restrict__ part,
                                                    float* __restrict__ stats,
                                                    int nblk, float invN){
  int t = threadIdx.x;
  int g = t & 31, ch = t >> 5;       // 8 chunks
  float s=0.f,q=0.f;
  for(int b=ch; b<nblk; b+=8){
    s += part[(b*32+g)*2+0];
    q += part[(b*32+g)*2+1];
  }
  __shared__ float ss[256], sq[256];
  ss[t]=s; sq[t]=q;
  __syncthreads();
  if(t<32){
    float a=0.f,bq=0.f;
    #pragma unroll
    for(int c=0;c<8;c++){ a+=ss[c*32+t]; bq+=sq[c*32+t]; }
    float m = a*invN;
    float v = bq*invN - m*m;
    stats[t*2+0]=m;
    stats[t*2+1]=rsqrtf(v+1e-5f);
  }
}

// ---------------- fold GN1 into W1 ----------------
__global__ __launch_bounds__(256) void w1fix_k(const float* __restrict__ w1,
                                               const float* __restrict__ b1,
                                               const float* __restrict__ stats,
                                               const float* __restrict__ gw,
                                               const float* __restrict__ gb,
                                               __bf16* __restrict__ wt1,
                                               float* __restrict__ b1p){
  int n = blockIdx.x, c = threadIdx.x;
  int g = c>>3;
  float m = stats[g*2+0], r = stats[g*2+1];
  float s = r*gw[c];
  float t = gb[c] - m*s;
  float w = w1[(size_t)c*1024 + n];
  wt1[(size_t)n*256 + c] = (__bf16)(s*w);
  __shared__ float red[256];
  red[c] = t*w; __syncthreads();
  for(int st=128; st>0; st>>=1){ if(c<st) red[c]+=red[c+st]; __syncthreads(); }
  if(c==0) b1p[n] = b1[n] + red[0];
}

// ---------------- fold GN2 into mh_w ----------------
__global__ __launch_bounds__(256) void w3fix_k(const float* __restrict__ mhw,
                                               const float* __restrict__ part2,
                                               const float* __restrict__ gw,
                                               const float* __restrict__ gb,
                                               __bf16* __restrict__ wt3,
                                               float* __restrict__ b3){
  __shared__ float st[16];
  __shared__ float ps[256], pq[256];
  int n = blockIdx.x, t = threadIdx.x;
  {
    int g = t & 7, ch = t >> 3;
    float s=0.f,q=0.f;
    for(int i=ch; i<91; i+=32){
      s += part2[(g*91+i)*2+0];
      q += part2[(g*91+i)*2+1];
    }
    ps[t]=s; pq[t]=q;
    __syncthreads();
    if(t<8){
      float a=0.f,bq=0.f;
      #pragma unroll
      for(int c=0;c<32;c++){ a+=ps[c*8+t]; bq+=pq[c*8+t]; }
      float m = a*(1.f/1048320.f);
      float v = bq*(1.f/1048320.f) - m*m;
      st[t*2+0]=m; st[t*2+1]=rsqrtf(v+1e-5f);
    }
    __syncthreads();
  }
  float bp=0.f;
  #pragma unroll
  for(int l=0;l<2;l++){
    int cc = t + l*256;
    int g = cc>>6;
    float m = st[g*2+0], r = st[g*2+1];
    float s = r*gw[cc];
    float tt = gb[cc] - m*s;
    float w = mhw[(size_t)cc*256 + n];
    wt3[(size_t)n*512 + cc] = (__bf16)(s*w);
    bp += tt*w;
  }
  __shared__ float red[256];
  red[t]=bp; __syncthreads();
  for(int stp=128;stp>0;stp>>=1){ if(t<stp) red[t]+=red[t+stp]; __syncthreads(); }
  if(t==0) b3[n]=red[0];
}

// ---------------- MFMA bf16 GEMM: BK=32, PING-PONG LDS double buffer ----------------
// One barrier per K-iter: sync (drains DMA issued a full compute-phase ago),
// issue DMA into other buffer, compute from current. DMA latency hidden by MFMA phase.
// Grid (row-fastest): all col-blocks of an A-row-tile share one XCD.
// Swizzle: 16B chunk c of LDS row r stored at phys chunk c ^ ((r>>1)&3) -> 2-way banks (free).
// OUTMODE: 0 = fp32 C, 1 = bf16 C, 2 = u2-split (cols<512 -> VB bf16 [h][m][j][c]; cols>=512 -> UM bf16 [pos][256])
template<int ACT, int OUTMODE>
__global__ __launch_bounds__(256) void gemm_ld(const __bf16* __restrict__ A,
                                               const __bf16* __restrict__ Bt,
                                               const float* __restrict__ bias,
                                               void* __restrict__ Cp,
                                               __bf16* __restrict__ VB,
                                               __bf16* __restrict__ UM,
                                               int M, int N, int K)
{
  __shared__ __bf16 As[2][128][32];
  __shared__ __bf16 Bs[2][128][32];
  const int tid  = threadIdx.x;
  const int lane = tid & 63, wave = tid >> 6;
  const int row0 = blockIdx.x*128, col0 = blockIdx.y*128;
  const int lrow = lane >> 2;                       // 16 rows per wave-load
  const int csw  = ((lane&3) ^ ((lane>>3)&3)) * 8;  // swizzled source chunk
  const int wr = (wave >> 1)*64, wc = (wave & 1)*64;
  const int m16 = lane & 15, quad = lane >> 4;
  const int pa = (quad ^ ((m16>>1)&3)) * 8;         // swizzled read chunk

  const __bf16* Ag0 = A  + (size_t)(row0 + wave*32 + lrow)*K + csw;
  const __bf16* Ag1 = Ag0 + (size_t)16*K;
  const __bf16* Bg0 = Bt + (size_t)(col0 + wave*32 + lrow)*K + csw;
  const __bf16* Bg1 = Bg0 + (size_t)16*K;

  floatx4 acc[4][4];
  #pragma unroll
  for(int i=0;i<4;i++)
    #pragma unroll
    for(int j=0;j<4;j++) acc[i][j] = (floatx4)0.f;

  // prologue: DMA first tile into buffer 0
  gl_lds16(Ag0, &As[0][wave*32     ][0]);
  gl_lds16(Ag1, &As[0][wave*32 + 16][0]);
  gl_lds16(Bg0, &Bs[0][wave*32     ][0]);
  gl_lds16(Bg1, &Bs[0][wave*32 + 16][0]);
  Ag0 += 32; Ag1 += 32; Bg0 += 32; Bg1 += 32;

  const int kiters = K >> 5;
  for(int kk=0; kk<kiters; kk++){
    const int cur = kk & 1;
    __syncthreads();                 // drains prior DMA (issued one compute-phase ago)
    if(kk+1 < kiters){
      const int nxt = cur^1;
      gl_lds16(Ag0, &As[nxt][wave*32     ][0]);
      gl_lds16(Ag1, &As[nxt][wave*32 + 16][0]);
      gl_lds16(Bg0, &Bs[nxt][wave*32     ][0]);
      gl_lds16(Bg1, &Bs[nxt][wave*32 + 16][0]);
      Ag0 += 32; Ag1 += 32; Bg0 += 32; Bg1 += 32;
    }
    bf16x8 af[4], bfv[4];
    #pragma unroll
    for(int ti=0;ti<4;ti++) af[ti]  = *(const bf16x8*)&As[cur][wr + ti*16 + m16][pa];
    #pragma unroll
    for(int tj=0;tj<4;tj++) bfv[tj] = *(const bf16x8*)&Bs[cur][wc + tj*16 + m16][pa];
    #pragma unroll
    for(int ti=0;ti<4;ti++)
      #pragma unroll
      for(int tj=0;tj<4;tj++)
        acc[ti][tj] = __builtin_amdgcn_mfma_f32_16x16x32_bf16(af[ti], bfv[tj], acc[ti][tj], 0,0,0);
  }

  #pragma unroll
  for(int ti=0;ti<4;ti++){
    #pragma unroll
    for(int reg=0;reg<4;reg++){
      int gr = row0 + wr + ti*16 + quad*4 + reg;
      if(gr >= M) continue;
      int jj = gr/180, mm = gr - jj*180;   // only used for OUTMODE 2
      #pragma unroll
      for(int tj=0;tj<4;tj++){
        int gc = col0 + wc + tj*16 + m16;
        float v = acc[ti][tj][reg];
        if(bias) v += bias[gc];
        if(ACT==1) v = gelu_tanh(v);
        if(OUTMODE==2){
          if(gc < 512){
            int hh = gc>>6, cc = gc&63;
            VB[(((size_t)(hh*180+mm)*91)+jj)*64 + cc] = (__bf16)v;
          } else {
            UM[(size_t)gr*256 + (gc-512)] = (__bf16)v;
          }
        } else if(OUTMODE==1){
          ((__bf16*)Cp)[(size_t)gr*N + gc] = (__bf16)v;
        } else {
          ((float*)Cp)[(size_t)gr*N + gc]  = v;
        }
      }
    }
  }
}

// ---------------- merged mean + pooling MLP: one dispatch, 271 blocks ----------------
__device__ __forceinline__ void pool_core(int r, int t, float y,
    const float* __restrict__ lnw, const float* __restrict__ lnb,
    const float* __restrict__ w1, const float* __restrict__ b1,
    const float* __restrict__ w2, const float* __restrict__ b2,
    float* __restrict__ out,
    float* xn, float* red, float* g){
  red[t]=y; __syncthreads();
  for(int s=128;s>0;s>>=1){ if(t<s) red[t]+=red[t+s]; __syncthreads(); }
  float m = red[0]*(1.f/256.f); __syncthreads();
  float d = y-m; red[t]=d*d; __syncthreads();
  for(int s=128;s>0;s>>=1){ if(t<s) red[t]+=red[t+s]; __syncthreads(); }
  float var = red[0]*(1.f/256.f);
  __syncthreads();
  xn[t] = d*rsqrtf(var+1e-5f)*lnw[t]+lnb[t];
  __syncthreads();
  float s1=b1[t], s2=b1[256+t];
  for(int c=0;c<256;c++){ float xv=xn[c]; s1 += xv*w1[c*512+t]; s2 += xv*w1[c*512+256+t]; }
  g[t] = gelu_tanh(s1)*s2;
  __syncthreads();
  float o=b2[t];
  for(int c=0;c<256;c++) o += g[c]*w2[c*256+t];
  out[r*256+t]=o;
}

__global__ __launch_bounds__(256) void mpool_k(
    const __bf16* __restrict__ um, const float* __restrict__ wlat,
    const float* __restrict__ tl_inw, const float* __restrict__ tl_lnw, const float* __restrict__ tl_lnb,
    const float* __restrict__ tl_w1, const float* __restrict__ tl_b1,
    const float* __restrict__ tl_w2, const float* __restrict__ tl_b2,
    const float* __restrict__ ta_inw, const float* __restrict__ ta_lnw, const float* __restrict__ ta_lnb,
    const float* __restrict__ ta_w1, const float* __restrict__ ta_b1,
    const float* __restrict__ ta_w2, const float* __restrict__ ta_b2,
    float* __restrict__ ulsrc, float* __restrict__ uasrc){
  __shared__ float xs[256], xn[256], red[256], g[256];
  int b = blockIdx.x, t = threadIdx.x;
  if(b < 180){
    float s=0.f;
    for(int j=0;j<91;j++) s += (float)um[(size_t)(j*180+b)*256 + t];
    xs[t] = s*(1.0f/91.0f);
    __syncthreads();
    float y=0.f;
    for(int c=0;c<256;c++) y += xs[c]*tl_inw[c*256+t];
    pool_core(b, t, y, tl_lnw, tl_lnb, tl_w1, tl_b1, tl_w2, tl_b2, ulsrc, xn, red, g);
  } else {
    int r = b-180;
    const __bf16* base = um + (size_t)r*180*256 + t;
    float s=0.f;
    for(int m=0;m<180;m++) s += (float)base[(size_t)m*256];
    xs[t] = s*(1.0f/180.0f);
    __syncthreads();
    float y=0.f;
    for(int c=0;c<256;c++) y += xs[c]*ta_inw[c*256+t];
    y *= wlat[r];
    pool_core(r, t, y, ta_lnw, ta_lnb, ta_w1, ta_b1, ta_w2, ta_b2, uasrc, xn, red, g);
  }
}

// ---------------- merged k-projection, transposed output out[col][r] ----------------
__global__ __launch_bounds__(256) void rowmmT2_k(const float* __restrict__ ulsrc,
                                                 const float* __restrict__ uasrc,
                                                 const float* __restrict__ wlong,
                                                 const float* __restrict__ wlatk,
                                                 float* __restrict__ klkl,
                                                 float* __restrict__ klka){
  int b = blockIdx.x, t = threadIdx.x;
  const float* X; const float* W; float* out; int r, R;
  if(b < 180){ r=b;     X=ulsrc; W=wlong; out=klkl; R=180; }
  else       { r=b-180; X=uasrc; W=wlatk; out=klka; R=91;  }
  int j = blockIdx.y*256 + t;
  __shared__ float xs[256];
  xs[t] = X[r*256 + t];
  __syncthreads();
  float s = 0.f;
  for(int c=0;c<256;c++) s += xs[c]*W[(size_t)c*1536 + j];
  out[(size_t)j*R + r] = s;
}

// ---------------- merged modulation tables, transposed out[(h*192+d)][m] ----------------
__global__ __launch_bounds__(256) void modu2_k(const float* __restrict__ lon,
                                               const float* __restrict__ lat,
                                               const float* __restrict__ flong,
                                               const float* __restrict__ flat,
                                               const float* __restrict__ wlong,
                                               const float* __restrict__ wlatm,
                                               float* __restrict__ modul,
                                               float* __restrict__ modua){
  int b = blockIdx.x, t = threadIdx.x;
  const float* coord; const float* freqs; const float* W; float* out;
  int h, m, nm, nk, periodic;
  if(b < 1440){ h=b/180; m=b%180; nm=180; nk=64; periodic=1; coord=lon; freqs=flong; W=wlong; out=modul; }
  else        { int b2=b-1440; h=b2/91; m=b2%91; nm=91; nk=32; periodic=0; coord=lat; freqs=flat; W=wlatm; out=modua; }
  __shared__ float basis[64];
  float dist = fabsf(coord[m] - coord[0]);
  if(periodic && dist > PI_F) dist = 2.f*PI_F - dist;
  float d = dist + 1e-5f;
  if(t < nk) basis[t] = 0.7978845608028654f * sinf(freqs[t]*d/PI_F) / d;
  __syncthreads();
  if(t < 192){
    float s=0.f;
    for(int k=0;k<nk;k++) s += basis[k]*W[(size_t)(k*8+h)*192+t];
    out[((size_t)h*192 + t)*nm + m] = s;
  }
}

// ---------------- merged low-rank kernels (coalesced d-major loads) -> padded bf16 ----------------
__global__ __launch_bounds__(256) void lrk2_k(const float* __restrict__ qlong,
                                              const float* __restrict__ qlat,
                                              const float* __restrict__ klkl,
                                              const float* __restrict__ klka,
                                              const float* __restrict__ modul,
                                              const float* __restrict__ modua,
                                              const float* __restrict__ wlat,
                                              __bf16* __restrict__ kbg,
                                              __bf16* __restrict__ kbl){
  int b = blockIdx.x, t = threadIdx.x;
  const float* qry; const float* kt; const float* mt; const float* js; __bf16* out;
  int h, i, n, pitch; float scale;
  if(b < 1440){ h=b/180; i=b%180; n=180; pitch=192; qry=qlong; kt=klkl; mt=modul; js=nullptr; out=kbg; scale=2.f*PI_F/180.f; }
  else        { int b2=b-1440; h=b2/91; i=b2%91; n=91; pitch=96; qry=qlat; kt=klka; mt=modua; js=wlat; out=kbl; scale=PI_F/91.f; }
  __shared__ float qs[192];
  if(t<192) qs[t] = qry[(size_t)i*1536 + h*192 + t];
  __syncthreads();
  int j = t;
  if(j < n){
    int m = abs(i-j);
    const float* kp = kt + (size_t)h*192*n;
    const float* mp = mt + (size_t)h*192*n;
    float s=0.f;
    #pragma unroll 4
    for(int d=0;d<192;d++) s += qs[d] * kp[(size_t)d*n + j] * mp[(size_t)d*n + m];
    s = (s>=0.f) ? s : 0.2f*s;
    if(js) s *= js[j];
    out[((size_t)h*pitch + i)*pitch + j] = (__bf16)(s*scale);
  }
}

// ---------------- apply1 MFMA: per (h,m): C[91,64] = klat[h](91x91) @ V(91x64) ----------------
// Epilogue staged through vst (reused as [91][72] bf16) -> 128B vector row stores.
__global__ __launch_bounds__(256) void apply1_mfma(const __bf16* __restrict__ Kl,
                                                   const __bf16* __restrict__ vbf,
                                                   __bf16* __restrict__ u1){
  int h = blockIdx.x / 180, m = blockIdx.x % 180;
  __shared__ __bf16 vst[64][104];           // 6656 elems; reused as ost[91][72]=6552
  int t = threadIdx.x;
  const __bf16* src = vbf + ((size_t)(h*180+m)*91)*64;
  for(int idx=t; idx<91*64; idx+=256){
    int j = idx>>6, c = idx&63;
    vst[c][j] = src[idx];
  }
  for(int idx=t; idx<64*13; idx+=256){
    int c = idx/13, j = 91 + idx - (idx/13)*13;
    vst[c][j] = (__bf16)0.f;
  }
  __syncthreads();
  int lane = t & 63, wave = t>>6;
  int m16 = lane & 15, quad = lane>>4;
  floatx4 acc[6];
  #pragma unroll
  for(int i=0;i<6;i++) acc[i]=(floatx4)0.f;
  const __bf16* Ab = Kl + (size_t)h*96*96;
  #pragma unroll
  for(int kc=0; kc<3; kc++){
    bf16x8 bfrag = *(const bf16x8*)&vst[wave*16 + m16][kc*32 + quad*8];
    #pragma unroll
    for(int ti=0;ti<6;ti++){
      bf16x8 afrag = *(const bf16x8*)&Ab[(size_t)(ti*16+m16)*96 + kc*32 + quad*8];
      acc[ti] = __builtin_amdgcn_mfma_f32_16x16x32_bf16(afrag, bfrag, acc[ti], 0,0,0);
    }
  }
  __syncthreads();                          // vst reads done; reuse as ost
  __bf16* ost = &vst[0][0];
  int c = wave*16 + m16;
  #pragma unroll
  for(int ti=0;ti<6;ti++){
    #pragma unroll
    for(int reg=0;reg<4;reg++){
      int i = ti*16 + quad*4 + reg;
      if(i<91) ost[i*72 + c] = (__bf16)acc[ti][reg];
    }
  }
  __syncthreads();
  __bf16* dst = u1 + (((size_t)(h*91)*180)+m)*64;
  for(int idx=t; idx<91*8; idx+=256){
    int i = idx>>3, cc = idx&7;
    *(bf16x8*)(dst + (size_t)i*180*64 + cc*8) = *(const bf16x8*)&ost[i*72 + cc*8];
  }
}

// ---------------- apply2 MFMA: A2 bf16 [pos][512] via staged 128B stores + GN2 partials ----------------
__global__ __launch_bounds__(256) void apply2_mfma(const __bf16* __restrict__ Kg,
                                                   const __bf16* __restrict__ u1,
                                                   __bf16* __restrict__ a2,
                                                   float* __restrict__ part2){
  int h = blockIdx.x / 91, i = blockIdx.x % 91;
  __shared__ __bf16 vst[64][208];           // 13312 elems; reused as ost[180][72]=12960
  __shared__ float rs[256], rq[256];
  int t = threadIdx.x;
  const __bf16* src = u1 + ((size_t)(h*91+i)*180)*64;
  for(int idx=t; idx<180*64; idx+=256){
    int m = idx>>6, c = idx&63;
    vst[c][m] = src[idx];
  }
  for(int idx=t; idx<64*28; idx+=256){
    int c = idx/28, m = 180 + idx - (idx/28)*28;
    vst[c][m] = (__bf16)0.f;
  }
  __syncthreads();
  int lane = t&63, wave = t>>6;
  int m16 = lane&15, quad = lane>>4;
  floatx4 acc[12];
  #pragma unroll
  for(int l=0;l<12;l++) acc[l]=(floatx4)0.f;
  const __bf16* Ab = Kg + (size_t)h*192*192;
  for(int kc=0; kc<6; kc++){
    bf16x8 bfrag = *(const bf16x8*)&vst[wave*16+m16][kc*32 + quad*8];
    #pragma unroll
    for(int tl=0; tl<12; tl++){
      bf16x8 afrag = *(const bf16x8*)&Ab[(size_t)(tl*16+m16)*192 + kc*32 + quad*8];
      acc[tl] = __builtin_amdgcn_mfma_f32_16x16x32_bf16(afrag, bfrag, acc[tl], 0,0,0);
    }
  }
  __syncthreads();                          // vst reads done; reuse as ost
  __bf16* ost = &vst[0][0];
  int c = wave*16+m16;
  float s=0.f, q=0.f;
  #pragma unroll
  for(int tl=0; tl<12; tl++){
    #pragma unroll
    for(int reg=0; reg<4; reg++){
      int l = tl*16 + quad*4 + reg;
      if(l<180){
        float v = acc[tl][reg];
        ost[l*72 + c] = (__bf16)v;
        s += v; q += v*v;
      }
    }
  }
  rs[t]=s; rq[t]=q;
  __syncthreads();
  for(int st=128; st>0; st>>=1){ if(t<st){ rs[t]+=rs[t+st]; rq[t]+=rq[t+st]; } __syncthreads(); }
  if(t==0){ part2[blockIdx.x*2+0]=rs[0]; part2[blockIdx.x*2+1]=rq[0]; }
  __bf16* dst = a2 + (size_t)i*180*512 + h*64;
  for(int idx=t; idx<180*8; idx+=256){
    int l = idx>>3, cc = idx&7;
    *(bf16x8*)(dst + (size_t)l*512 + cc*8) = *(const bf16x8*)&ost[l*72 + cc*8];
  }
}

// ---------------------------------------------------------------------------
extern "C" void kernel_launch(void* const* d_in, const int* in_sizes, int n_in,
                              void* d_out, int out_size, void* d_ws, size_t ws_size,
                              hipStream_t stream){
  const float* u_src      = (const float*)d_in[0];
  const float* u_lat_qry  = (const float*)d_in[1];
  const float* u_long_qry = (const float*)d_in[2];
  const float* lat = (const float*)d_in[3];
  const float* lon = (const float*)((in_sizes[4]==180)? d_in[4] : d_in[5]);
  const float* cm_gn_w = (const float*)d_in[7];
  const float* cm_gn_b = (const float*)d_in[8];
  const float* cm_w1   = (const float*)d_in[9];
  const float* cm_b1   = (const float*)d_in[10];
  const float* cm_w2   = (const float*)d_in[11];
  const float* cm_b2   = (const float*)d_in[12];
  const float* tl_in_w = (const float*)d_in[13];
  const float* tl_ln_w = (const float*)d_in[14];
  const float* tl_ln_b = (const float*)d_in[15];
  const float* tl_w1   = (const float*)d_in[16];
  const float* tl_b1   = (const float*)d_in[17];
  const float* tl_w2   = (const float*)d_in[18];
  const float* tl_b2   = (const float*)d_in[19];
  const float* ta_in_w = (const float*)d_in[20];
  const float* ta_ln_w = (const float*)d_in[21];
  const float* ta_ln_b = (const float*)d_in[22];
  const float* ta_w1   = (const float*)d_in[23];
  const float* ta_b1   = (const float*)d_in[24];
  const float* ta_w2   = (const float*)d_in[25];
  const float* ta_b2   = (const float*)d_in[26];
  const float* klong_wk= (const float*)d_in[27];
  const float* klat_wk = (const float*)d_in[28];
  const float* pe_long_freq = (const float*)d_in[29];
  const float* pe_long_w    = (const float*)d_in[30];
  const float* pe_lat_freq  = (const float*)d_in[31];
  const float* pe_lat_w     = (const float*)d_in[32];
  const float* mh_gn_w = (const float*)d_in[33];
  const float* mh_gn_b = (const float*)d_in[34];
  const float* mh_w    = (const float*)d_in[35];

  float* ws = (float*)d_ws;
  const size_t OFF_PART1  = 0;          // 32768
  const size_t OFF_GN1    = 32768;      // 64
  const size_t OFF_WLAT   = 32896;      // 91
  const size_t OFF_ULSRC  = 33024;      // 46080
  const size_t OFF_UASRC  = 79104;      // 23296
  const size_t OFF_KLKL   = 102400;     // 276480 fp32 kprojT long [1536][180]
  const size_t OFF_KLKA   = 378880;     // 139776 fp32 kprojT lat  [1536][91]
  const size_t OFF_MODUL  = 518656;     // 276480 fp32 modT long [1536][180]
  const size_t OFF_MODUA  = 795136;     // 139776 fp32 modT lat  [1536][91]
  const size_t OFF_KBL    = 934912;     // bf16 8*96*96   -> 36864 f
  const size_t OFF_KBG    = 971776;     // bf16 8*192*192 -> 147456 f -> ends 1119232
  const size_t OFF_PART2  = 1119232;    // 1456
  const size_t OFF_B1P    = 1120688;    // 1024
  const size_t OFF_B3     = 1121712;    // 256
  const size_t OFF_WT1    = 1122048;    // bf16 [1024][256] -> 131072 f
  const size_t OFF_WT2    = 1253120;    // bf16 [768][1024] -> 393216 f
  const size_t OFF_WT3    = 1646336;    // bf16 [256][512]  -> 65536 f -> ends 1711872
  const size_t OFF_VBF    = 1711872;    // bf16 [8][180][91][64] -> 4193280 f
  const size_t OFF_A2     = 1711872;    // bf16 [16380][512] (reuses VBF post-apply1)
  const size_t OFF_UMID   = 5905152;    // bf16 [16380][256] -> 2096640 f
  const size_t OFF_H1     = 8001792;    // bf16 16380x1024 -> 8386560 f
  const size_t OFF_U1     = 8001792;    // bf16 (reuses H1)
  const size_t OFF_A1     = 16388352;   // bf16 16380x256 -> ends 18484992 (~74 MB)

  const int NPOS = 16380;

  // 1) prep (zfill + wcvt w2 + wlat)
  prep_k<<<4513,256,0,stream>>>(cm_w2, (__bf16*)(ws+OFF_WT2), (__bf16*)(ws+OFF_KBL),
      lat, ws+OFF_WLAT);

  // 2) GN1 partials + bf16 cast of u_src, parallel final reduce
  gn1cast_k<<<512,256,0,stream>>>(u_src, (__bf16*)(ws+OFF_A1), ws+OFF_PART1, NPOS);
  gn_final_par<<<1,256,0,stream>>>(ws+OFF_PART1, ws+OFF_GN1, 512, 1.f/131040.f);

  // 3) fold GN1 into W1
  w1fix_k<<<1024,256,0,stream>>>(cm_w1, cm_b1, ws+OFF_GN1, cm_gn_w, cm_gn_b,
      (__bf16*)(ws+OFF_WT1), ws+OFF_B1P);

  // 4) h1 = gelu(A1 @ W1' + b1')  [16380 x 1024] bf16
  gemm_ld<1,1><<<dim3(128,8),256,0,stream>>>((const __bf16*)(ws+OFF_A1),
      (const __bf16*)(ws+OFF_WT1), ws+OFF_B1P, ws+OFF_H1, nullptr, nullptr, NPOS, 1024, 256);

  // 5) u2 = h1 @ W2 + b2: cols<512 -> vbf bf16; cols>=512 -> umid bf16
  gemm_ld<0,2><<<dim3(128,6),256,0,stream>>>((const __bf16*)(ws+OFF_H1),
      (const __bf16*)(ws+OFF_WT2), cm_b2, nullptr, (__bf16*)(ws+OFF_VBF),
      (__bf16*)(ws+OFF_UMID), NPOS, 768, 1024);

  // 6) merged mean + pooling MLPs
  mpool_k<<<271,256,0,stream>>>((const __bf16*)(ws+OFF_UMID), ws+OFF_WLAT,
      tl_in_w, tl_ln_w, tl_ln_b, tl_w1, tl_b1, tl_w2, tl_b2,
      ta_in_w, ta_ln_w, ta_ln_b, ta_w1, ta_b1, ta_w2, ta_b2,
      ws+OFF_ULSRC, ws+OFF_UASRC);

  // 7) merged k-projections (transposed)
  rowmmT2_k<<<dim3(271,6),256,0,stream>>>(ws+OFF_ULSRC, ws+OFF_UASRC, klong_wk, klat_wk,
      ws+OFF_KLKL, ws+OFF_KLKA);

  // 8) merged modulation tables (transposed)
  modu2_k<<<2168,256,0,stream>>>(lon, lat, pe_long_freq, pe_lat_freq, pe_long_w, pe_lat_w,
      ws+OFF_MODUL, ws+OFF_MODUA);

  // 9) merged low-rank kernels -> padded bf16
  lrk2_k<<<2168,256,0,stream>>>(u_long_qry, u_lat_qry, ws+OFF_KLKL, ws+OFF_KLKA,
      ws+OFF_MODUL, ws+OFF_MODUA, ws+OFF_WLAT, (__bf16*)(ws+OFF_KBG), (__bf16*)(ws+OFF_KBL));

  // 10) kernel application (MFMA, vectorized epilogues); apply2 emits A2 + GN2 partials
  apply1_mfma<<<8*180,256,0,stream>>>((const __bf16*)(ws+OFF_KBL), (const __bf16*)(ws+OFF_VBF),
      (__bf16*)(ws+OFF_U1));
  apply2_mfma<<<8*91, 256,0,stream>>>((const __bf16*)(ws+OFF_KBG), (const __bf16*)(ws+OFF_U1),
      (__bf16*)(ws+OFF_A2), ws+OFF_PART2);

  // 11) fold GN2 into mh_w, then final projection
  w3fix_k<<<256,256,0,stream>>>(mh_w, ws+OFF_PART2, mh_gn_w, mh_gn_b,
      (__bf16*)(ws+OFF_WT3), ws+OFF_B3);
  gemm_ld<0,0><<<dim3(128,2),256,0,stream>>>((const __bf16*)(ws+OFF_A2),
      (const __bf16*)(ws+OFF_WT3), ws+OFF_B3, (float*)d_out, nullptr, nullptr, NPOS, 256, 512);
}

// Round 11
// 406.193 us; speedup vs baseline: 1.1200x; 1.0475x over previous
//
#include <hip/hip_runtime.h>
#include <math.h>

#define PI_F 3.14159265358979323846f

typedef __bf16  bf16x8  __attribute__((ext_vector_type(8)));
typedef float   floatx4 __attribute__((ext_vector_type(4)));

// tanh-gelu via fast exp: 0.5x(1+tanh(y)) == x*sigmoid(2y)
__device__ __forceinline__ float gelu_tanh(float x){
  float z = 1.5957691216f*x + 0.07135481283f*x*x*x;
  return x / (1.f + __expf(-z));
}

// async global->LDS 16B per lane; LDS dest = wave-uniform base + lane*16
__device__ __forceinline__ void gl_lds16(const void* g, void* l){
  __builtin_amdgcn_global_load_lds(
      (const __attribute__((address_space(1))) void*)(uintptr_t)g,
      (__attribute__((address_space(3))) void*)(uintptr_t)l,
      16, 0, 0);
}

// ---------------- prep: zfill K buffers + wcvt cm_w2 + wlat (one dispatch) ----------------
__global__ __launch_bounds__(256) void prep_k(const float* __restrict__ w2in,
                                              __bf16* __restrict__ wt2,
                                              __bf16* __restrict__ kbuf,
                                              const float* __restrict__ lat,
                                              float* __restrict__ wlat){
  int b = blockIdx.x, t = threadIdx.x;
  if(b < 1440){
    int i = b*256 + t;
    if(i < 368640) kbuf[i] = (__bf16)0.f;
  } else if(b < 4512){
    int idx = (b-1440)*256 + t;   // 786432 total
    int n = idx >> 10, k = idx & 1023;      // wt2[n][k] = w2[k][n], N=768,K=1024
    wt2[idx] = (__bf16)w2in[(size_t)k*768 + n];
  } else {
    if(t < 91) wlat[t] = cosf(lat[t]);
    __syncthreads();
    if(t == 0){
      float dlat = lat[1]-lat[0];
      float s4 = sinf(dlat*0.25f);
      float pw = s4*s4 / sinf(dlat*0.5f);
      if(wlat[0]  < 0.001f) wlat[0]  = pw;
      if(wlat[90] < 0.001f) wlat[90] = pw;
    }
  }
}

// ---------------- GN1 partial stats + plain bf16 cast of u_src (512 blocks) ----------------
__global__ __launch_bounds__(256) void gn1cast_k(const float* __restrict__ x,
                                                 __bf16* __restrict__ xa,
                                                 float* __restrict__ part, int npos){
  int c = threadIdx.x;
  float s=0.f, q=0.f;
  for(int p=blockIdx.x; p<npos; p+=gridDim.x){
    float v = x[p*256 + c];
    xa[p*256 + c] = (__bf16)v;
    s += v; q += v*v;
  }
  __shared__ float ss[256], sq[256];
  ss[c]=s; sq[c]=q;
  __syncthreads();
  if((c&7)==0){
    float a=0.f,b=0.f;
    #pragma unroll
    for(int k=0;k<8;k++){ a+=ss[c+k]; b+=sq[c+k]; }
    int g=c>>3;
    part[(blockIdx.x*32+g)*2+0]=a;
    part[(blockIdx.x*32+g)*2+1]=b;
  }
}

// ---------------- parallel GN final reduce ----------------
__global__ __launch_bounds__(256) void gn_final_par(const float* __restrict__ part,
                                                    float* __restrict__ stats,
                                                    int nblk, float invN){
  int t = threadIdx.x;
  int g = t & 31, ch = t >> 5;       // 8 chunks
  float s=0.f,q=0.f;
  for(int b=ch; b<nblk; b+=8){
    s += part[(b*32+g)*2+0];
    q += part[(b*32+g)*2+1];
  }
  __shared__ float ss[256], sq[256];
  ss[t]=s; sq[t]=q;
  __syncthreads();
  if(t<32){
    float a=0.f,bq=0.f;
    #pragma unroll
    for(int c=0;c<8;c++){ a+=ss[c*32+t]; bq+=sq[c*32+t]; }
    float m = a*invN;
    float v = bq*invN - m*m;
    stats[t*2+0]=m;
    stats[t*2+1]=rsqrtf(v+1e-5f);
  }
}

// ---------------- fold GN1 into W1 ----------------
__global__ __launch_bounds__(256) void w1fix_k(const float* __restrict__ w1,
                                               const float* __restrict__ b1,
                                               const float* __restrict__ stats,
                                               const float* __restrict__ gw,
                                               const float* __restrict__ gb,
                                               __bf16* __restrict__ wt1,
                                               float* __restrict__ b1p){
  int n = blockIdx.x, c = threadIdx.x;
  int g = c>>3;
  float m = stats[g*2+0], r = stats[g*2+1];
  float s = r*gw[c];
  float t = gb[c] - m*s;
  float w = w1[(size_t)c*1024 + n];
  wt1[(size_t)n*256 + c] = (__bf16)(s*w);
  __shared__ float red[256];
  red[c] = t*w; __syncthreads();
  for(int st=128; st>0; st>>=1){ if(c<st) red[c]+=red[c+st]; __syncthreads(); }
  if(c==0) b1p[n] = b1[n] + red[0];
}

// ---------------- fold GN2 into mh_w ----------------
__global__ __launch_bounds__(256) void w3fix_k(const float* __restrict__ mhw,
                                               const float* __restrict__ part2,
                                               const float* __restrict__ gw,
                                               const float* __restrict__ gb,
                                               __bf16* __restrict__ wt3,
                                               float* __restrict__ b3){
  __shared__ float st[16];
  __shared__ float ps[256], pq[256];
  int n = blockIdx.x, t = threadIdx.x;
  {
    int g = t & 7, ch = t >> 3;
    float s=0.f,q=0.f;
    for(int i=ch; i<91; i+=32){
      s += part2[(g*91+i)*2+0];
      q += part2[(g*91+i)*2+1];
    }
    ps[t]=s; pq[t]=q;
    __syncthreads();
    if(t<8){
      float a=0.f,bq=0.f;
      #pragma unroll
      for(int c=0;c<32;c++){ a+=ps[c*8+t]; bq+=pq[c*8+t]; }
      float m = a*(1.f/1048320.f);
      float v = bq*(1.f/1048320.f) - m*m;
      st[t*2+0]=m; st[t*2+1]=rsqrtf(v+1e-5f);
    }
    __syncthreads();
  }
  float bp=0.f;
  #pragma unroll
  for(int l=0;l<2;l++){
    int cc = t + l*256;
    int g = cc>>6;
    float m = st[g*2+0], r = st[g*2+1];
    float s = r*gw[cc];
    float tt = gb[cc] - m*s;
    float w = mhw[(size_t)cc*256 + n];
    wt3[(size_t)n*512 + cc] = (__bf16)(s*w);
    bp += tt*w;
  }
  __shared__ float red[256];
  red[t]=bp; __syncthreads();
  for(int stp=128;stp>0;stp>>=1){ if(t<stp) red[t]+=red[t+stp]; __syncthreads(); }
  if(t==0) b3[n]=red[0];
}

// ---------------- MFMA bf16 GEMM: BK=32, ping-pong LDS, LDS-staged C writes ----------------
// smem (32KB) = As[2][128][32] | Bs[2][128][32] during K-loop; reused as C-stage [128][128] bf16.
// One barrier per K-iter (drains DMA issued a full compute-phase ago).
// Grid (row-fastest): all col-blocks of an A-row-tile share one XCD.
// OUTMODE: 0 = fp32 C direct, 1 = bf16 C staged, 2 = u2-split staged (whole block is VB or UM since 128|col0)
template<int ACT, int OUTMODE>
__global__ __launch_bounds__(256) void gemm_ld(const __bf16* __restrict__ A,
                                               const __bf16* __restrict__ Bt,
                                               const float* __restrict__ bias,
                                               void* __restrict__ Cp,
                                               __bf16* __restrict__ VB,
                                               __bf16* __restrict__ UM,
                                               int M, int N, int K)
{
  __shared__ __bf16 smem[16384];
  __bf16* Asb = smem;            // [2][128][32]
  __bf16* Bsb = smem + 8192;     // [2][128][32]
  const int tid  = threadIdx.x;
  const int lane = tid & 63, wave = tid >> 6;
  const int row0 = blockIdx.x*128, col0 = blockIdx.y*128;
  const int lrow = lane >> 2;                       // 16 rows per wave-load
  const int csw  = ((lane&3) ^ ((lane>>3)&3)) * 8;  // swizzled source chunk
  const int wr = (wave >> 1)*64, wc = (wave & 1)*64;
  const int m16 = lane & 15, quad = lane >> 4;
  const int pa = (quad ^ ((m16>>1)&3)) * 8;         // swizzled read chunk

  const __bf16* Ag0 = A  + (size_t)(row0 + wave*32 + lrow)*K + csw;
  const __bf16* Ag1 = Ag0 + (size_t)16*K;
  const __bf16* Bg0 = Bt + (size_t)(col0 + wave*32 + lrow)*K + csw;
  const __bf16* Bg1 = Bg0 + (size_t)16*K;

  floatx4 acc[4][4];
  #pragma unroll
  for(int i=0;i<4;i++)
    #pragma unroll
    for(int j=0;j<4;j++) acc[i][j] = (floatx4)0.f;

  // prologue: DMA first tile into buffer 0
  gl_lds16(Ag0, Asb + (wave*32     )*32);
  gl_lds16(Ag1, Asb + (wave*32 + 16)*32);
  gl_lds16(Bg0, Bsb + (wave*32     )*32);
  gl_lds16(Bg1, Bsb + (wave*32 + 16)*32);
  Ag0 += 32; Ag1 += 32; Bg0 += 32; Bg1 += 32;

  const int kiters = K >> 5;
  for(int kk=0; kk<kiters; kk++){
    const int cur = (kk & 1) * 4096;
    __syncthreads();                 // drains prior DMA (issued one compute-phase ago)
    if(kk+1 < kiters){
      const int nxt = 4096 - cur;
      gl_lds16(Ag0, Asb + nxt + (wave*32     )*32);
      gl_lds16(Ag1, Asb + nxt + (wave*32 + 16)*32);
      gl_lds16(Bg0, Bsb + nxt + (wave*32     )*32);
      gl_lds16(Bg1, Bsb + nxt + (wave*32 + 16)*32);
      Ag0 += 32; Ag1 += 32; Bg0 += 32; Bg1 += 32;
    }
    bf16x8 af[4], bfv[4];
    #pragma unroll
    for(int ti=0;ti<4;ti++) af[ti]  = *(const bf16x8*)&Asb[cur + (wr + ti*16 + m16)*32 + pa];
    #pragma unroll
    for(int tj=0;tj<4;tj++) bfv[tj] = *(const bf16x8*)&Bsb[cur + (wc + tj*16 + m16)*32 + pa];
    #pragma unroll
    for(int ti=0;ti<4;ti++)
      #pragma unroll
      for(int tj=0;tj<4;tj++)
        acc[ti][tj] = __builtin_amdgcn_mfma_f32_16x16x32_bf16(af[ti], bfv[tj], acc[ti][tj], 0,0,0);
  }

  if(OUTMODE==0){
    // direct fp32 stores (64B runs)
    #pragma unroll
    for(int ti=0;ti<4;ti++){
      #pragma unroll
      for(int reg=0;reg<4;reg++){
        int gr = row0 + wr + ti*16 + quad*4 + reg;
        if(gr >= M) continue;
        #pragma unroll
        for(int tj=0;tj<4;tj++){
          int gc = col0 + wc + tj*16 + m16;
          float v = acc[ti][tj][reg];
          if(bias) v += bias[gc];
          ((float*)Cp)[(size_t)gr*N + gc] = v;
        }
      }
    }
  } else {
    // stage bf16 tile in smem (K-loop buffers dead after final barrier)
    __syncthreads();
    #pragma unroll
    for(int ti=0;ti<4;ti++){
      #pragma unroll
      for(int reg=0;reg<4;reg++){
        int r = wr + ti*16 + quad*4 + reg;
        #pragma unroll
        for(int tj=0;tj<4;tj++){
          int c = wc + tj*16 + m16;
          float v = acc[ti][tj][reg];
          if(bias) v += bias[col0 + c];
          if(ACT==1) v = gelu_tanh(v);
          smem[r*128 + c] = (__bf16)v;
        }
      }
    }
    __syncthreads();
    if(OUTMODE==1){
      for(int idx=tid; idx<2048; idx+=256){
        int r = idx>>4, ch = (idx&15)*8;
        int gr = row0 + r;
        if(gr < M)
          *(bf16x8*)((__bf16*)Cp + (size_t)gr*N + col0 + ch) = *(const bf16x8*)&smem[r*128 + ch];
      }
    } else if(col0 < 512){
      // VB: bf16 [h][m][j][64]; 128B runs per 64-channel head chunk
      for(int idx=tid; idx<2048; idx+=256){
        int r = idx>>4, ch = (idx&15)*8;
        int gr = row0 + r;
        if(gr < M){
          int jj = gr/180, mm = gr - jj*180;
          int gc = col0 + ch, hh = gc>>6, cc = gc&63;
          *(bf16x8*)&VB[(((size_t)(hh*180+mm)*91)+jj)*64 + cc] = *(const bf16x8*)&smem[r*128 + ch];
        }
      }
    } else {
      // UM: bf16 [pos][256]; 256B rows
      for(int idx=tid; idx<2048; idx+=256){
        int r = idx>>4, ch = (idx&15)*8;
        int gr = row0 + r;
        if(gr < M)
          *(bf16x8*)&UM[(size_t)gr*256 + (col0-512) + ch] = *(const bf16x8*)&smem[r*128 + ch];
      }
    }
  }
}

// ---------------- merged mean + pooling MLP: one dispatch, 271 blocks ----------------
__device__ __forceinline__ void pool_core(int r, int t, float y,
    const float* __restrict__ lnw, const float* __restrict__ lnb,
    const float* __restrict__ w1, const float* __restrict__ b1,
    const float* __restrict__ w2, const float* __restrict__ b2,
    float* __restrict__ out,
    float* xn, float* red, float* g){
  red[t]=y; __syncthreads();
  for(int s=128;s>0;s>>=1){ if(t<s) red[t]+=red[t+s]; __syncthreads(); }
  float m = red[0]*(1.f/256.f); __syncthreads();
  float d = y-m; red[t]=d*d; __syncthreads();
  for(int s=128;s>0;s>>=1){ if(t<s) red[t]+=red[t+s]; __syncthreads(); }
  float var = red[0]*(1.f/256.f);
  __syncthreads();
  xn[t] = d*rsqrtf(var+1e-5f)*lnw[t]+lnb[t];
  __syncthreads();
  float s1=b1[t], s2=b1[256+t];
  for(int c=0;c<256;c++){ float xv=xn[c]; s1 += xv*w1[c*512+t]; s2 += xv*w1[c*512+256+t]; }
  g[t] = gelu_tanh(s1)*s2;
  __syncthreads();
  float o=b2[t];
  for(int c=0;c<256;c++) o += g[c]*w2[c*256+t];
  out[r*256+t]=o;
}

__global__ __launch_bounds__(256) void mpool_k(
    const __bf16* __restrict__ um, const float* __restrict__ wlat,
    const float* __restrict__ tl_inw, const float* __restrict__ tl_lnw, const float* __restrict__ tl_lnb,
    const float* __restrict__ tl_w1, const float* __restrict__ tl_b1,
    const float* __restrict__ tl_w2, const float* __restrict__ tl_b2,
    const float* __restrict__ ta_inw, const float* __restrict__ ta_lnw, const float* __restrict__ ta_lnb,
    const float* __restrict__ ta_w1, const float* __restrict__ ta_b1,
    const float* __restrict__ ta_w2, const float* __restrict__ ta_b2,
    float* __restrict__ ulsrc, float* __restrict__ uasrc){
  __shared__ float xs[256], xn[256], red[256], g[256];
  int b = blockIdx.x, t = threadIdx.x;
  if(b < 180){
    float s=0.f;
    for(int j=0;j<91;j++) s += (float)um[(size_t)(j*180+b)*256 + t];
    xs[t] = s*(1.0f/91.0f);
    __syncthreads();
    float y=0.f;
    for(int c=0;c<256;c++) y += xs[c]*tl_inw[c*256+t];
    pool_core(b, t, y, tl_lnw, tl_lnb, tl_w1, tl_b1, tl_w2, tl_b2, ulsrc, xn, red, g);
  } else {
    int r = b-180;
    const __bf16* base = um + (size_t)r*180*256 + t;
    float s=0.f;
    for(int m=0;m<180;m++) s += (float)base[(size_t)m*256];
    xs[t] = s*(1.0f/180.0f);
    __syncthreads();
    float y=0.f;
    for(int c=0;c<256;c++) y += xs[c]*ta_inw[c*256+t];
    y *= wlat[r];
    pool_core(r, t, y, ta_lnw, ta_lnb, ta_w1, ta_b1, ta_w2, ta_b2, uasrc, xn, red, g);
  }
}

// ---------------- merged k-projection, transposed output out[col][r] ----------------
__global__ __launch_bounds__(256) void rowmmT2_k(const float* __restrict__ ulsrc,
                                                 const float* __restrict__ uasrc,
                                                 const float* __restrict__ wlong,
                                                 const float* __restrict__ wlatk,
                                                 float* __restrict__ klkl,
                                                 float* __restrict__ klka){
  int b = blockIdx.x, t = threadIdx.x;
  const float* X; const float* W; float* out; int r, R;
  if(b < 180){ r=b;     X=ulsrc; W=wlong; out=klkl; R=180; }
  else       { r=b-180; X=uasrc; W=wlatk; out=klka; R=91;  }
  int j = blockIdx.y*256 + t;
  __shared__ float xs[256];
  xs[t] = X[r*256 + t];
  __syncthreads();
  float s = 0.f;
  for(int c=0;c<256;c++) s += xs[c]*W[(size_t)c*1536 + j];
  out[(size_t)j*R + r] = s;
}

// ---------------- merged modulation tables, transposed out[(h*192+d)][m] ----------------
__global__ __launch_bounds__(256) void modu2_k(const float* __restrict__ lon,
                                               const float* __restrict__ lat,
                                               const float* __restrict__ flong,
                                               const float* __restrict__ flat,
                                               const float* __restrict__ wlong,
                                               const float* __restrict__ wlatm,
                                               float* __restrict__ modul,
                                               float* __restrict__ modua){
  int b = blockIdx.x, t = threadIdx.x;
  const float* coord; const float* freqs; const float* W; float* out;
  int h, m, nm, nk, periodic;
  if(b < 1440){ h=b/180; m=b%180; nm=180; nk=64; periodic=1; coord=lon; freqs=flong; W=wlong; out=modul; }
  else        { int b2=b-1440; h=b2/91; m=b2%91; nm=91; nk=32; periodic=0; coord=lat; freqs=flat; W=wlatm; out=modua; }
  __shared__ float basis[64];
  float dist = fabsf(coord[m] - coord[0]);
  if(periodic && dist > PI_F) dist = 2.f*PI_F - dist;
  float d = dist + 1e-5f;
  if(t < nk) basis[t] = 0.7978845608028654f * sinf(freqs[t]*d/PI_F) / d;
  __syncthreads();
  if(t < 192){
    float s=0.f;
    for(int k=0;k<nk;k++) s += basis[k]*W[(size_t)(k*8+h)*192+t];
    out[((size_t)h*192 + t)*nm + m] = s;
  }
}

// ---------------- merged low-rank kernels (coalesced d-major loads) -> padded bf16 ----------------
__global__ __launch_bounds__(256) void lrk2_k(const float* __restrict__ qlong,
                                              const float* __restrict__ qlat,
                                              const float* __restrict__ klkl,
                                              const float* __restrict__ klka,
                                              const float* __restrict__ modul,
                                              const float* __restrict__ modua,
                                              const float* __restrict__ wlat,
                                              __bf16* __restrict__ kbg,
                                              __bf16* __restrict__ kbl){
  int b = blockIdx.x, t = threadIdx.x;
  const float* qry; const float* kt; const float* mt; const float* js; __bf16* out;
  int h, i, n, pitch; float scale;
  if(b < 1440){ h=b/180; i=b%180; n=180; pitch=192; qry=qlong; kt=klkl; mt=modul; js=nullptr; out=kbg; scale=2.f*PI_F/180.f; }
  else        { int b2=b-1440; h=b2/91; i=b2%91; n=91; pitch=96; qry=qlat; kt=klka; mt=modua; js=wlat; out=kbl; scale=PI_F/91.f; }
  __shared__ float qs[192];
  if(t<192) qs[t] = qry[(size_t)i*1536 + h*192 + t];
  __syncthreads();
  int j = t;
  if(j < n){
    int m = abs(i-j);
    const float* kp = kt + (size_t)h*192*n;
    const float* mp = mt + (size_t)h*192*n;
    float s=0.f;
    #pragma unroll 4
    for(int d=0;d<192;d++) s += qs[d] * kp[(size_t)d*n + j] * mp[(size_t)d*n + m];
    s = (s>=0.f) ? s : 0.2f*s;
    if(js) s *= js[j];
    out[((size_t)h*pitch + i)*pitch + j] = (__bf16)(s*scale);
  }
}

// ---------------- apply1 MFMA: per (h,m): C[91,64] = klat[h](91x91) @ V(91x64) ----------------
__global__ __launch_bounds__(256) void apply1_mfma(const __bf16* __restrict__ Kl,
                                                   const __bf16* __restrict__ vbf,
                                                   __bf16* __restrict__ u1){
  int h = blockIdx.x / 180, m = blockIdx.x % 180;
  __shared__ __bf16 vst[64][104];           // 6656 elems; reused as ost[91][72]=6552
  int t = threadIdx.x;
  const __bf16* src = vbf + ((size_t)(h*180+m)*91)*64;
  for(int idx=t; idx<91*64; idx+=256){
    int j = idx>>6, c = idx&63;
    vst[c][j] = src[idx];
  }
  for(int idx=t; idx<64*13; idx+=256){
    int c = idx/13, j = 91 + idx - (idx/13)*13;
    vst[c][j] = (__bf16)0.f;
  }
  __syncthreads();
  int lane = t & 63, wave = t>>6;
  int m16 = lane & 15, quad = lane>>4;
  floatx4 acc[6];
  #pragma unroll
  for(int i=0;i<6;i++) acc[i]=(floatx4)0.f;
  const __bf16* Ab = Kl + (size_t)h*96*96;
  #pragma unroll
  for(int kc=0; kc<3; kc++){
    bf16x8 bfrag = *(const bf16x8*)&vst[wave*16 + m16][kc*32 + quad*8];
    #pragma unroll
    for(int ti=0;ti<6;ti++){
      bf16x8 afrag = *(const bf16x8*)&Ab[(size_t)(ti*16+m16)*96 + kc*32 + quad*8];
      acc[ti] = __builtin_amdgcn_mfma_f32_16x16x32_bf16(afrag, bfrag, acc[ti], 0,0,0);
    }
  }
  __syncthreads();                          // vst reads done; reuse as ost
  __bf16* ost = &vst[0][0];
  int c = wave*16 + m16;
  #pragma unroll
  for(int ti=0;ti<6;ti++){
    #pragma unroll
    for(int reg=0;reg<4;reg++){
      int i = ti*16 + quad*4 + reg;
      if(i<91) ost[i*72 + c] = (__bf16)acc[ti][reg];
    }
  }
  __syncthreads();
  __bf16* dst = u1 + (((size_t)(h*91)*180)+m)*64;
  for(int idx=t; idx<91*8; idx+=256){
    int i = idx>>3, cc = idx&7;
    *(bf16x8*)(dst + (size_t)i*180*64 + cc*8) = *(const bf16x8*)&ost[i*72 + cc*8];
  }
}

// ---------------- apply2 MFMA: A2 bf16 [pos][512] via staged 128B stores + GN2 partials ----------------
__global__ __launch_bounds__(256) void apply2_mfma(const __bf16* __restrict__ Kg,
                                                   const __bf16* __restrict__ u1,
                                                   __bf16* __restrict__ a2,
                                                   float* __restrict__ part2){
  int h = blockIdx.x / 91, i = blockIdx.x % 91;
  __shared__ __bf16 vst[64][208];           // 13312 elems; reused as ost[180][72]=12960
  __shared__ float rs[256], rq[256];
  int t = threadIdx.x;
  const __bf16* src = u1 + ((size_t)(h*91+i)*180)*64;
  for(int idx=t; idx<180*64; idx+=256){
    int m = idx>>6, c = idx&63;
    vst[c][m] = src[idx];
  }
  for(int idx=t; idx<64*28; idx+=256){
    int c = idx/28, m = 180 + idx - (idx/28)*28;
    vst[c][m] = (__bf16)0.f;
  }
  __syncthreads();
  int lane = t&63, wave = t>>6;
  int m16 = lane&15, quad = lane>>4;
  floatx4 acc[12];
  #pragma unroll
  for(int l=0;l<12;l++) acc[l]=(floatx4)0.f;
  const __bf16* Ab = Kg + (size_t)h*192*192;
  for(int kc=0; kc<6; kc++){
    bf16x8 bfrag = *(const bf16x8*)&vst[wave*16+m16][kc*32 + quad*8];
    #pragma unroll
    for(int tl=0; tl<12; tl++){
      bf16x8 afrag = *(const bf16x8*)&Ab[(size_t)(tl*16+m16)*192 + kc*32 + quad*8];
      acc[tl] = __builtin_amdgcn_mfma_f32_16x16x32_bf16(afrag, bfrag, acc[tl], 0,0,0);
    }
  }
  __syncthreads();                          // vst reads done; reuse as ost
  __bf16* ost = &vst[0][0];
  int c = wave*16+m16;
  float s=0.f, q=0.f;
  #pragma unroll
  for(int tl=0; tl<12; tl++){
    #pragma unroll
    for(int reg=0; reg<4; reg++){
      int l = tl*16 + quad*4 + reg;
      if(l<180){
        float v = acc[tl][reg];
        ost[l*72 + c] = (__bf16)v;
        s += v; q += v*v;
      }
    }
  }
  rs[t]=s; rq[t]=q;
  __syncthreads();
  for(int st=128; st>0; st>>=1){ if(t<st){ rs[t]+=rs[t+st]; rq[t]+=rq[t+st]; } __syncthreads(); }
  if(t==0){ part2[blockIdx.x*2+0]=rs[0]; part2[blockIdx.x*2+1]=rq[0]; }
  __bf16* dst = a2 + (size_t)i*180*512 + h*64;
  for(int idx=t; idx<180*8; idx+=256){
    int l = idx>>3, cc = idx&7;
    *(bf16x8*)(dst + (size_t)l*512 + cc*8) = *(const bf16x8*)&ost[l*72 + cc*8];
  }
}

// ---------------------------------------------------------------------------
extern "C" void kernel_launch(void* const* d_in, const int* in_sizes, int n_in,
                              void* d_out, int out_size, void* d_ws, size_t ws_size,
                              hipStream_t stream){
  const float* u_src      = (const float*)d_in[0];
  const float* u_lat_qry  = (const float*)d_in[1];
  const float* u_long_qry = (const float*)d_in[2];
  const float* lat = (const float*)d_in[3];
  const float* lon = (const float*)((in_sizes[4]==180)? d_in[4] : d_in[5]);
  const float* cm_gn_w = (const float*)d_in[7];
  const float* cm_gn_b = (const float*)d_in[8];
  const float* cm_w1   = (const float*)d_in[9];
  const float* cm_b1   = (const float*)d_in[10];
  const float* cm_w2   = (const float*)d_in[11];
  const float* cm_b2   = (const float*)d_in[12];
  const float* tl_in_w = (const float*)d_in[13];
  const float* tl_ln_w = (const float*)d_in[14];
  const float* tl_ln_b = (const float*)d_in[15];
  const float* tl_w1   = (const float*)d_in[16];
  const float* tl_b1   = (const float*)d_in[17];
  const float* tl_w2   = (const float*)d_in[18];
  const float* tl_b2   = (const float*)d_in[19];
  const float* ta_in_w = (const float*)d_in[20];
  const float* ta_ln_w = (const float*)d_in[21];
  const float* ta_ln_b = (const float*)d_in[22];
  const float* ta_w1   = (const float*)d_in[23];
  const float* ta_b1   = (const float*)d_in[24];
  const float* ta_w2   = (const float*)d_in[25];
  const float* ta_b2   = (const float*)d_in[26];
  const float* klong_wk= (const float*)d_in[27];
  const float* klat_wk = (const float*)d_in[28];
  const float* pe_long_freq = (const float*)d_in[29];
  const float* pe_long_w    = (const float*)d_in[30];
  const float* pe_lat_freq  = (const float*)d_in[31];
  const float* pe_lat_w     = (const float*)d_in[32];
  const float* mh_gn_w = (const float*)d_in[33];
  const float* mh_gn_b = (const float*)d_in[34];
  const float* mh_w    = (const float*)d_in[35];

  float* ws = (float*)d_ws;
  const size_t OFF_PART1  = 0;          // 32768
  const size_t OFF_GN1    = 32768;      // 64
  const size_t OFF_WLAT   = 32896;      // 91
  const size_t OFF_ULSRC  = 33024;      // 46080
  const size_t OFF_UASRC  = 79104;      // 23296
  const size_t OFF_KLKL   = 102400;     // 276480 fp32 kprojT long [1536][180]
  const size_t OFF_KLKA   = 378880;     // 139776 fp32 kprojT lat  [1536][91]
  const size_t OFF_MODUL  = 518656;     // 276480 fp32 modT long [1536][180]
  const size_t OFF_MODUA  = 795136;     // 139776 fp32 modT lat  [1536][91]
  const size_t OFF_KBL    = 934912;     // bf16 8*96*96   -> 36864 f
  const size_t OFF_KBG    = 971776;     // bf16 8*192*192 -> 147456 f -> ends 1119232
  const size_t OFF_PART2  = 1119232;    // 1456
  const size_t OFF_B1P    = 1120688;    // 1024
  const size_t OFF_B3     = 1121712;    // 256
  const size_t OFF_WT1    = 1122048;    // bf16 [1024][256] -> 131072 f
  const size_t OFF_WT2    = 1253120;    // bf16 [768][1024] -> 393216 f
  const size_t OFF_WT3    = 1646336;    // bf16 [256][512]  -> 65536 f -> ends 1711872
  const size_t OFF_VBF    = 1711872;    // bf16 [8][180][91][64] -> 4193280 f
  const size_t OFF_A2     = 1711872;    // bf16 [16380][512] (reuses VBF post-apply1)
  const size_t OFF_UMID   = 5905152;    // bf16 [16380][256] -> 2096640 f
  const size_t OFF_H1     = 8001792;    // bf16 16380x1024 -> 8386560 f
  const size_t OFF_U1     = 8001792;    // bf16 (reuses H1)
  const size_t OFF_A1     = 16388352;   // bf16 16380x256 -> ends 18484992 (~74 MB)

  const int NPOS = 16380;

  // 1) prep (zfill + wcvt w2 + wlat)
  prep_k<<<4513,256,0,stream>>>(cm_w2, (__bf16*)(ws+OFF_WT2), (__bf16*)(ws+OFF_KBL),
      lat, ws+OFF_WLAT);

  // 2) GN1 partials + bf16 cast of u_src, parallel final reduce
  gn1cast_k<<<512,256,0,stream>>>(u_src, (__bf16*)(ws+OFF_A1), ws+OFF_PART1, NPOS);
  gn_final_par<<<1,256,0,stream>>>(ws+OFF_PART1, ws+OFF_GN1, 512, 1.f/131040.f);

  // 3) fold GN1 into W1
  w1fix_k<<<1024,256,0,stream>>>(cm_w1, cm_b1, ws+OFF_GN1, cm_gn_w, cm_gn_b,
      (__bf16*)(ws+OFF_WT1), ws+OFF_B1P);

  // 4) h1 = gelu(A1 @ W1' + b1')  [16380 x 1024] bf16
  gemm_ld<1,1><<<dim3(128,8),256,0,stream>>>((const __bf16*)(ws+OFF_A1),
      (const __bf16*)(ws+OFF_WT1), ws+OFF_B1P, ws+OFF_H1, nullptr, nullptr, NPOS, 1024, 256);

  // 5) u2 = h1 @ W2 + b2: cols<512 -> vbf bf16; cols>=512 -> umid bf16
  gemm_ld<0,2><<<dim3(128,6),256,0,stream>>>((const __bf16*)(ws+OFF_H1),
      (const __bf16*)(ws+OFF_WT2), cm_b2, nullptr, (__bf16*)(ws+OFF_VBF),
      (__bf16*)(ws+OFF_UMID), NPOS, 768, 1024);

  // 6) merged mean + pooling MLPs
  mpool_k<<<271,256,0,stream>>>((const __bf16*)(ws+OFF_UMID), ws+OFF_WLAT,
      tl_in_w, tl_ln_w, tl_ln_b, tl_w1, tl_b1, tl_w2, tl_b2,
      ta_in_w, ta_ln_w, ta_ln_b, ta_w1, ta_b1, ta_w2, ta_b2,
      ws+OFF_ULSRC, ws+OFF_UASRC);

  // 7) merged k-projections (transposed)
  rowmmT2_k<<<dim3(271,6),256,0,stream>>>(ws+OFF_ULSRC, ws+OFF_UASRC, klong_wk, klat_wk,
      ws+OFF_KLKL, ws+OFF_KLKA);

  // 8) merged modulation tables (transposed)
  modu2_k<<<2168,256,0,stream>>>(lon, lat, pe_long_freq, pe_lat_freq, pe_long_w, pe_lat_w,
      ws+OFF_MODUL, ws+OFF_MODUA);

  // 9) merged low-rank kernels -> padded bf16
  lrk2_k<<<2168,256,0,stream>>>(u_long_qry, u_lat_qry, ws+OFF_KLKL, ws+OFF_KLKA,
      ws+OFF_MODUL, ws+OFF_MODUA, ws+OFF_WLAT, (__bf16*)(ws+OFF_KBG), (__bf16*)(ws+OFF_KBL));

  // 10) kernel application (MFMA, vectorized epilogues); apply2 emits A2 + GN2 partials
  apply1_mfma<<<8*180,256,0,stream>>>((const __bf16*)(ws+OFF_KBL), (const __bf16*)(ws+OFF_VBF),
      (__bf16*)(ws+OFF_U1));
  apply2_mfma<<<8*91, 256,0,stream>>>((const __bf16*)(ws+OFF_KBG), (const __bf16*)(ws+OFF_U1),
      (__bf16*)(ws+OFF_A2), ws+OFF_PART2);

  // 11) fold GN2 into mh_w, then final projection
  w3fix_k<<<256,256,0,stream>>>(mh_w, ws+OFF_PART2, mh_gn_w, mh_gn_b,
      (__bf16*)(ws+OFF_WT3), ws+OFF_B3);
  gemm_ld<0,0><<<dim3(128,2),256,0,stream>>>((const __bf16*)(ws+OFF_A2),
      (const __bf16*)(ws+OFF_WT3), ws+OFF_B3, (float*)d_out, nullptr, nullptr, NPOS, 256, 512);
}